// Round 5
// baseline (1395.936 us; speedup 1.0000x reference)
//
#include <hip/hip_runtime.h>
#include <hip/hip_bf16.h>
#include <math.h>

typedef __bf16 bf16;
typedef __bf16 bf16x8 __attribute__((ext_vector_type(8)));
typedef float f32x4 __attribute__((ext_vector_type(4)));

#define MP    4224      // padded token rows (33*128)
#define MACT  4100      // B*N = 4*1025
#define NQTOK 1025
#define NKTOK 1024
#define EDIM  1024
#define FDIM  4096
#define NHEAD 16
#define HD    64
#define QSCALE 0.125f

// flag slots
#define SX    0
#define SY    1
#define SQKVW 2
#define SPW   3
#define SCQW  4
#define SCKVW 5
#define SCPW  6
#define SFC1  7
#define SFC2  8
#define SRPB1 9
#define SRPB2 10
#define S1D   11

// scalar external load, dtype-dispatched
__device__ __forceinline__ float ldx(const void* p, size_t i, bool f32) {
  return f32 ? ((const float*)p)[i] : (float)(((const bf16*)p)[i]);
}
// 8-wide external load -> bf16x8, dtype-dispatched
__device__ __forceinline__ bf16x8 ld8(const void* p, size_t i, bool f32) {
  if (f32) {
    const float* q = (const float*)p + i;
    bf16x8 r;
#pragma unroll
    for (int j = 0; j < 8; ++j) r[j] = (bf16)q[j];
    return r;
  }
  return *(const bf16x8*)((const bf16*)p + i);
}
__device__ __forceinline__ bool getf(const int* flags, int slot) {
  return slot >= 0 && flags[slot] != 0;
}

// ---- per-array dtype probe: scan 4096 bf16-interpreted elements; any
// ---- exp==0xFF or denormal => data cannot be bf16 => fp32. Exact-value
// ---- probe for 1-D params via norm1_g (all-ones).
__global__ void dtype_probe_kernel(
    const void* x, const void* y, const void* w0, const void* w1,
    const void* w2, const void* w3, const void* w4, const void* w5,
    const void* w6, const void* r0, const void* r1, const void* oneg,
    int* flags)
{
  __shared__ int bad[11];
  const void* arrs[11] = {x, y, w0, w1, w2, w3, w4, w5, w6, r0, r1};
  const int tid = threadIdx.x;
  if (tid < 11) bad[tid] = 0;
  __syncthreads();
  for (int a = 0; a < 11; ++a) {
    const unsigned short* p = (const unsigned short*)arrs[a];
    int isbad = 0;
#pragma unroll
    for (int j = 0; j < 16; ++j) {
      unsigned short e = p[tid * 16 + j];
      unsigned ex = (e >> 7) & 0xFFu;
      if (ex == 0xFFu || (ex == 0u && (e & 0x7Fu) != 0u)) isbad = 1;
    }
    if (isbad) bad[a] = 1;
  }
  __syncthreads();
  if (tid < 11) flags[tid] = bad[tid];
  if (tid == 11) flags[S1D] = (((const unsigned*)oneg)[0] == 0x3F800000u) ? 1 : 0;
}

// ---------------- zero the pad rows of hln (shared LN-out / attn-out) ----
__global__ void zero_pads_kernel(bf16* hln) {
  int i = blockIdx.x * 256 + threadIdx.x;
  const int n = (MP - MACT) * EDIM;
  if (i < n) hln[(size_t)MACT * EDIM + i] = (bf16)0.0f;
}

// ---------------- LayerNorm (one block per token) ----------------
template<bool FIRST>
__global__ __launch_bounds__(256) void ln_kernel(const void* __restrict__ src,
    float* __restrict__ xf, bf16* __restrict__ out,
    const void* __restrict__ g, const void* __restrict__ bta,
    const int* __restrict__ flags, int sslot) {
  const bool f32s = getf(flags, sslot);
  const bool f32d = getf(flags, S1D);
  const int row = blockIdx.x;
  const int tid = threadIdx.x;
  float v[4];
  if (FIRST) {
#pragma unroll
    for (int i = 0; i < 4; ++i) {
      v[i] = ldx(src, (size_t)row * EDIM + tid + i * 256, f32s);
      xf[(size_t)row * EDIM + tid + i * 256] = v[i];
    }
  } else {
    const float* x = (const float*)src + (size_t)row * EDIM;
#pragma unroll
    for (int i = 0; i < 4; ++i) v[i] = x[tid + i * 256];
  }
  float s = 0.f, sq = 0.f;
#pragma unroll
  for (int i = 0; i < 4; ++i) { s += v[i]; sq += v[i] * v[i]; }
#pragma unroll
  for (int m = 32; m >= 1; m >>= 1) {
    s += __shfl_xor(s, m);
    sq += __shfl_xor(sq, m);
  }
  __shared__ float ss[4], ssq[4];
  const int wave = tid >> 6;
  if ((tid & 63) == 0) { ss[wave] = s; ssq[wave] = sq; }
  __syncthreads();
  s = ss[0] + ss[1] + ss[2] + ss[3];
  sq = ssq[0] + ssq[1] + ssq[2] + ssq[3];
  const float mean = s * (1.f / EDIM);
  const float var = sq * (1.f / EDIM) - mean * mean;
  const float rstd = rsqrtf(var + 1e-5f);
#pragma unroll
  for (int i = 0; i < 4; ++i) {
    int e = tid + i * 256;
    out[(size_t)row * EDIM + e] =
        (bf16)((v[i] - mean) * rstd * ldx(g, e, f32d) + ldx(bta, e, f32d));
  }
}

// ---------------- GEMM: C[m,n] = sum_k A[m,k]*B[n,k], fused epilogues ----
enum { EPI_QKV = 0, EPI_KV = 1, EPI_Q = 2, EPI_RES = 3, EPI_GELU = 4, EPI_FINAL = 5 };

template<int EPI>
__global__ __launch_bounds__(256) void gemm_bt(
    const void* __restrict__ A, const void* __restrict__ Bw,
    int K, int Nn,
    const void* __restrict__ bias0, const void* __restrict__ bias1,
    const void* __restrict__ gamma, float* __restrict__ xf,
    bf16* __restrict__ out0, bf16* __restrict__ out1, bf16* __restrict__ out2,
    float* __restrict__ outf,
    const int* __restrict__ flags, int aslot, int bslot)
{
  const bool f32a = getf(flags, aslot);
  const bool f32b = getf(flags, bslot);
  const bool f32d = getf(flags, S1D);
  __shared__ bf16 As[128][40];   // pad 32->40: 2-way LDS aliasing only (free)
  __shared__ bf16 Bs[128][40];
  const int tid = threadIdx.x;
  const int lane = tid & 63, wave = tid >> 6;
  const int quad = lane >> 4, l16 = lane & 15;
  const int wr = wave >> 1, wc = wave & 1;
  const int m0 = blockIdx.y * 128, n0 = blockIdx.x * 128;
  const int r0 = tid >> 2, c0 = (tid & 3) * 8;

  const size_t arow = (size_t)(m0 + r0);
  const size_t brow = (size_t)(n0 + r0);

  f32x4 acc[4][4];
#pragma unroll
  for (int i = 0; i < 4; ++i)
#pragma unroll
    for (int j = 0; j < 4; ++j)
#pragma unroll
      for (int r = 0; r < 4; ++r) acc[i][j][r] = 0.f;

  for (int k0 = 0; k0 < K; k0 += 32) {
    *(bf16x8*)(&As[r0][c0])      = ld8(A,  arow * K + k0 + c0,        f32a);
    *(bf16x8*)(&As[r0 + 64][c0]) = ld8(A, (arow + 64) * K + k0 + c0,  f32a);
    *(bf16x8*)(&Bs[r0][c0])      = ld8(Bw, brow * K + k0 + c0,        f32b);
    *(bf16x8*)(&Bs[r0 + 64][c0]) = ld8(Bw, (brow + 64) * K + k0 + c0, f32b);
    __syncthreads();
    bf16x8 af[4], bfv[4];
#pragma unroll
    for (int i = 0; i < 4; ++i) {
      af[i]  = *(const bf16x8*)(&As[wr * 64 + i * 16 + l16][quad * 8]);
      bfv[i] = *(const bf16x8*)(&Bs[wc * 64 + i * 16 + l16][quad * 8]);
    }
#pragma unroll
    for (int mb = 0; mb < 4; ++mb)
#pragma unroll
      for (int nb = 0; nb < 4; ++nb)
        acc[mb][nb] = __builtin_amdgcn_mfma_f32_16x16x32_bf16(af[mb], bfv[nb], acc[mb][nb], 0, 0, 0);
    __syncthreads();
  }

  // epilogue: C element (mb,nb,r): gm row, gn col
#pragma unroll
  for (int mb = 0; mb < 4; ++mb) {
#pragma unroll
    for (int r = 0; r < 4; ++r) {
      const int gm = m0 + wr * 64 + mb * 16 + quad * 4 + r;
#pragma unroll
      for (int nb = 0; nb < 4; ++nb) {
        const int gn = n0 + wc * 64 + nb * 16 + l16;
        float v = acc[mb][nb][r];
        if (EPI == EPI_QKV) {
          if (gm < MACT) {
            unsigned b = (unsigned)gm / 1025u;
            unsigned t = (unsigned)gm - b * 1025u;
            int sec = gn >> 10, e = gn & 1023;
            int h = e >> 6, d = e & 63;
            size_t o = ((size_t)(b * NHEAD + h) * NQTOK + t) * HD + d;
            if (sec == 0)      out0[o] = (bf16)((v + ldx(bias0, e, f32d)) * QSCALE);
            else if (sec == 1) out1[o] = (bf16)v;
            else               out2[o] = (bf16)(v + ldx(bias1, e, f32d));
          }
        } else if (EPI == EPI_KV) {
          unsigned b = (unsigned)gm >> 10;
          unsigned t = (unsigned)gm & 1023u;
          int sec = gn >> 10, e = gn & 1023;
          int h = e >> 6, d = e & 63;
          size_t o = ((size_t)(b * NHEAD + h) * NKTOK + t) * HD + d;
          if (sec == 0) out0[o] = (bf16)v;
          else          out1[o] = (bf16)(v + ldx(bias1, e, f32d));
        } else if (EPI == EPI_Q) {
          if (gm < MACT) {
            unsigned b = (unsigned)gm / 1025u;
            unsigned t = (unsigned)gm - b * 1025u;
            int h = gn >> 6, d = gn & 63;
            out0[((size_t)(b * NHEAD + h) * NQTOK + t) * HD + d] =
                (bf16)((v + ldx(bias0, gn, f32d)) * QSCALE);
          }
        } else if (EPI == EPI_RES) {
          if (gm < MACT) {
            size_t o = (size_t)gm * EDIM + gn;
            xf[o] += ldx(gamma, gn, f32d) * (v + ldx(bias0, gn, f32d));
          }
        } else if (EPI == EPI_GELU) {
          float z = v + ldx(bias0, gn, f32d);
          float ge = 0.5f * z * (1.0f + erff(z * 0.70710678118f));
          out0[(size_t)gm * Nn + gn] = (bf16)ge;
        } else { // EPI_FINAL — d_out is FLOAT (reference output dtype = f32)
          if (gm < MACT) {
            size_t o = (size_t)gm * EDIM + gn;
            outf[o] = xf[o] + ldx(gamma, gn, f32d) * (v + ldx(bias0, gn, f32d));
          }
        }
      }
    }
  }
}

// ---------------- Flash attention (self: causal+rpb, cross: rpb) --------
// grid (17, H, B), block 256 = 4 waves; 64-query tile, 64-key chunks.
template<bool CROSS>
__global__ __launch_bounds__(256) void attn_kernel(
    const bf16* __restrict__ Q, const bf16* __restrict__ Kg,
    const bf16* __restrict__ Vg, const void* __restrict__ rpb,
    bf16* __restrict__ out, const int* __restrict__ flags, int rslot)
{
  const bool f32r = getf(flags, rslot);
  const int NK  = CROSS ? NKTOK : NQTOK;
  const int NRD = CROSS ? 3970 : 3972;
  const int qt = blockIdx.x, h = blockIdx.y, b = blockIdx.z;
  const int tid = threadIdx.x;
  const int lane = tid & 63, wave = tid >> 6;
  const int quad = lane >> 4, l16 = lane & 15;

  __shared__ float rpb_s[4096];
  __shared__ bf16 Ks[64][72];
  __shared__ bf16 Vs[64][72];
  __shared__ bf16 Ps[4][16][72];

  for (int i = tid; i < 4096; i += 256)
    rpb_s[i] = (i < NRD) ? ldx(rpb, (size_t)i * NHEAD + h, f32r) : 0.f;

  const int q0 = qt * 64;
  const int qrow = q0 + wave * 16 + l16;
  const size_t qhb = (size_t)(b * NHEAD + h) * NQTOK;
  bf16x8 qf0, qf1;
  if (qrow < NQTOK) {
    qf0 = *(const bf16x8*)(Q + (qhb + qrow) * HD + quad * 8);
    qf1 = *(const bf16x8*)(Q + (qhb + qrow) * HD + 32 + quad * 8);
  } else {
#pragma unroll
    for (int j = 0; j < 8; ++j) { qf0[j] = (bf16)0.f; qf1[j] = (bf16)0.f; }
  }

  float m_run[4], l_run[4];
  f32x4 oacc[4];
#pragma unroll
  for (int r = 0; r < 4; ++r) { m_run[r] = -1e30f; l_run[r] = 0.f; }
#pragma unroll
  for (int d = 0; d < 4; ++d)
#pragma unroll
    for (int r = 0; r < 4; ++r) oacc[d][r] = 0.f;

  const size_t kvb = (size_t)(b * NHEAD + h) * NK;
  const int nch = CROSS ? (NKTOK / 64) : (qt + 1);  // causal chunk skipping

  for (int c = 0; c < nch; ++c) {
    const int kc = c * 64;
    __syncthreads();   // protect Ks/Vs (and first-iter rpb_s) reuse
#pragma unroll
    for (int vv = 0; vv < 2; ++vv) {
      int vi = tid + vv * 256;
      int rr = vi >> 3, co = (vi & 7) * 8;
      int krow = kc + rr;
      bf16x8 k8, v8;
      if (!CROSS && krow >= NK) {
#pragma unroll
        for (int j = 0; j < 8; ++j) { k8[j] = (bf16)0.f; v8[j] = (bf16)0.f; }
      } else {
        k8 = *(const bf16x8*)(Kg + (kvb + krow) * HD + co);
        v8 = *(const bf16x8*)(Vg + (kvb + krow) * HD + co);
      }
      *(bf16x8*)(&Ks[rr][co]) = k8;
      *(bf16x8*)(&Vs[rr][co]) = v8;
    }
    __syncthreads();

    // ---- S = Q K^T + bias (+causal) ----
    float sv[4][4];
#pragma unroll
    for (int kb = 0; kb < 4; ++kb) {
      f32x4 a;
#pragma unroll
      for (int r = 0; r < 4; ++r) a[r] = 0.f;
      bf16x8 kf0 = *(const bf16x8*)(&Ks[kb * 16 + l16][quad * 8]);
      bf16x8 kf1 = *(const bf16x8*)(&Ks[kb * 16 + l16][32 + quad * 8]);
      a = __builtin_amdgcn_mfma_f32_16x16x32_bf16(qf0, kf0, a, 0, 0, 0);
      a = __builtin_amdgcn_mfma_f32_16x16x32_bf16(qf1, kf1, a, 0, 0, 0);
      const int kg = kc + kb * 16 + l16;
#pragma unroll
      for (int r = 0; r < 4; ++r) {
        const int qg = q0 + wave * 16 + quad * 4 + r;
        bool valid = (kg < NK) && (CROSS || kg <= qg);
        int idx;
        if (CROSS) {
          if (qg == 0) idx = 3969;
          else {
            int p = qg - 1;
            int dr = (p >> 5) - (kg >> 5);
            int dc = (p & 31) - (kg & 31);
            idx = (dr + 31) * 63 + (dc + 31);
          }
        } else {
          if (qg == 0 && kg == 0) idx = 3971;
          else if (qg == 0) idx = 3969;
          else if (kg == 0) idx = 3970;
          else {
            int p = qg - 1, sk = kg - 1;
            int dr = (p >> 5) - (sk >> 5);
            int dc = (p & 31) - (sk & 31);
            idx = (dr + 31) * 63 + (dc + 31);
          }
        }
        idx = idx < 0 ? 0 : (idx > 4095 ? 4095 : idx);
        sv[kb][r] = valid ? (a[r] + rpb_s[idx]) : -1e30f;
      }
    }

    // ---- online softmax (row stats live in the 16 lanes of each quad) ----
#pragma unroll
    for (int r = 0; r < 4; ++r) {
      float mx = fmaxf(fmaxf(sv[0][r], sv[1][r]), fmaxf(sv[2][r], sv[3][r]));
#pragma unroll
      for (int mk = 8; mk >= 1; mk >>= 1) mx = fmaxf(mx, __shfl_xor(mx, mk));
      const float mnew = fmaxf(m_run[r], mx);
      const float alpha = __expf(m_run[r] - mnew);
      m_run[r] = mnew;
      float rs = 0.f;
#pragma unroll
      for (int kb = 0; kb < 4; ++kb) {
        float p = __expf(sv[kb][r] - mnew);
        rs += p;
        Ps[wave][quad * 4 + r][kb * 16 + l16] = (bf16)p;
      }
#pragma unroll
      for (int mk = 8; mk >= 1; mk >>= 1) rs += __shfl_xor(rs, mk);
      l_run[r] = l_run[r] * alpha + rs;
#pragma unroll
      for (int d = 0; d < 4; ++d) oacc[d][r] *= alpha;
    }

    // Drain the Ps ds_writes before the cross-lane A-layout reads.
    __syncthreads();

    // ---- O += P V  (P via per-wave LDS round-trip into A-layout) ----
    bf16x8 pf0 = *(const bf16x8*)(&Ps[wave][l16][quad * 8]);
    bf16x8 pf1 = *(const bf16x8*)(&Ps[wave][l16][32 + quad * 8]);
#pragma unroll
    for (int db = 0; db < 4; ++db) {
      bf16x8 vf0, vf1;
#pragma unroll
      for (int j = 0; j < 8; ++j) {
        vf0[j] = Vs[quad * 8 + j][db * 16 + l16];
        vf1[j] = Vs[32 + quad * 8 + j][db * 16 + l16];
      }
      oacc[db] = __builtin_amdgcn_mfma_f32_16x16x32_bf16(pf0, vf0, oacc[db], 0, 0, 0);
      oacc[db] = __builtin_amdgcn_mfma_f32_16x16x32_bf16(pf1, vf1, oacc[db], 0, 0, 0);
    }
  }

  // ---- write O ----
#pragma unroll
  for (int r = 0; r < 4; ++r) {
    const int qg = q0 + wave * 16 + quad * 4 + r;
    if (qg < NQTOK) {
      const float inv = 1.f / l_run[r];
      const size_t row = (size_t)b * NQTOK + qg;
#pragma unroll
      for (int db = 0; db < 4; ++db)
        out[row * EDIM + h * HD + db * 16 + l16] = (bf16)(oacc[db][r] * inv);
    }
  }
}

// ---------------- launch ----------------
extern "C" void kernel_launch(void* const* d_in, const int* in_sizes, int n_in,
                              void* d_out, int out_size, void* d_ws, size_t ws_size,
                              hipStream_t stream) {
  (void)in_sizes; (void)n_in; (void)out_size; (void)ws_size;
  const void* x        = d_in[0];
  const void* y        = d_in[1];
  const void* n1g      = d_in[2];
  const void* n1b      = d_in[3];
  const void* n2g      = d_in[4];
  const void* n2b      = d_in[5];
  const void* n3g      = d_in[6];
  const void* n3b      = d_in[7];
  const void* sa_qkv_w = d_in[8];
  const void* sa_qb    = d_in[9];
  const void* sa_vb    = d_in[10];
  const void* sa_rpb   = d_in[11];
  const void* sa_pw    = d_in[12];
  const void* sa_pb    = d_in[13];
  const void* ca_qw    = d_in[14];
  const void* ca_kvw   = d_in[15];
  const void* ca_qb    = d_in[16];
  const void* ca_vb    = d_in[17];
  const void* ca_rpb   = d_in[18];
  const void* ca_pw    = d_in[19];
  const void* ca_pb    = d_in[20];
  const void* fc1_w    = d_in[21];
  const void* fc1_b    = d_in[22];
  const void* fc2_w    = d_in[23];
  const void* fc2_b    = d_in[24];
  const void* g1       = d_in[25];
  const void* g2       = d_in[26];
  const void* g3       = d_in[27];
  float* outf = (float*)d_out;     // reference output dtype is float32

  // Workspace layout (~60.6 MB):
  //   flags : int[64] dtype flags
  //   xf    : fp32 residual, MP*EDIM*4            (16.9 MB)
  //   hln   : LN-out / attn-out bf16, MP*EDIM*2   ( 8.7 MB)
  //   h1    : FFN hidden bf16, MP*FDIM*2          (34.6 MB)  [qt/kt/vt alias head]
  char* w = (char*)d_ws;
  int* flags = (int*)w;   w += 256;
  float* xf = (float*)w;  w += (size_t)MP * EDIM * 4;
  bf16* hln = (bf16*)w;   w += (size_t)MP * EDIM * 2;
  char* big = w;          // MP*FDIM*2 = 34.6 MB reserved
  const size_t qkv_sz = (size_t)4 * NHEAD * NQTOK * HD * 2;  // 8.4 MB
  bf16* qt = (bf16*)big;
  bf16* kt = (bf16*)(big + qkv_sz);
  bf16* vt = (bf16*)(big + 2 * qkv_sz);
  bf16* h1 = (bf16*)big;          // aliases qt/kt/vt (dead by FFN)

  dtype_probe_kernel<<<1, 256, 0, stream>>>(
      x, y, sa_qkv_w, sa_pw, ca_qw, ca_kvw, ca_pw, fc1_w, fc2_w,
      sa_rpb, ca_rpb, n1g, flags);
  zero_pads_kernel<<<dim3(((MP - MACT) * EDIM + 255) / 256), 256, 0, stream>>>(hln);

  // --- self-attention block ---
  ln_kernel<true><<<MACT, 256, 0, stream>>>(x, xf, hln, n1g, n1b, flags, SX);
  gemm_bt<EPI_QKV><<<dim3(24, 33), 256, 0, stream>>>(hln, sa_qkv_w, 1024, 3072,
      sa_qb, sa_vb, nullptr, nullptr, qt, kt, vt, nullptr, flags, -1, SQKVW);
  attn_kernel<false><<<dim3(17, NHEAD, 4), 256, 0, stream>>>(qt, kt, vt, sa_rpb, hln, flags, SRPB1);
  gemm_bt<EPI_RES><<<dim3(8, 33), 256, 0, stream>>>(hln, sa_pw, 1024, 1024,
      sa_pb, nullptr, g1, xf, nullptr, nullptr, nullptr, nullptr, flags, -1, SPW);

  // --- cross-attention block ---
  ln_kernel<false><<<MACT, 256, 0, stream>>>(xf, nullptr, hln, n2g, n2b, flags, -1);
  gemm_bt<EPI_Q><<<dim3(8, 33), 256, 0, stream>>>(hln, ca_qw, 1024, 1024,
      ca_qb, nullptr, nullptr, nullptr, qt, nullptr, nullptr, nullptr, flags, -1, SCQW);
  gemm_bt<EPI_KV><<<dim3(16, 32), 256, 0, stream>>>(y, ca_kvw, 1024, 2048,
      nullptr, ca_vb, nullptr, nullptr, kt, vt, nullptr, nullptr, flags, SY, SCKVW);
  attn_kernel<true><<<dim3(17, NHEAD, 4), 256, 0, stream>>>(qt, kt, vt, ca_rpb, hln, flags, SRPB2);
  gemm_bt<EPI_RES><<<dim3(8, 33), 256, 0, stream>>>(hln, ca_pw, 1024, 1024,
      ca_pb, nullptr, g2, xf, nullptr, nullptr, nullptr, nullptr, flags, -1, SCPW);

  // --- FFN ---
  ln_kernel<false><<<MACT, 256, 0, stream>>>(xf, nullptr, hln, n3g, n3b, flags, -1);
  gemm_bt<EPI_GELU><<<dim3(32, 33), 256, 0, stream>>>(hln, fc1_w, 1024, 4096,
      fc1_b, nullptr, nullptr, nullptr, h1, nullptr, nullptr, nullptr, flags, -1, SFC1);
  gemm_bt<EPI_FINAL><<<dim3(8, 33), 256, 0, stream>>>(h1, fc2_w, 4096, 1024,
      fc2_b, nullptr, g3, xf, nullptr, nullptr, nullptr, outf, flags, -1, SFC2);
}

// Round 6
// 1298.014 us; speedup vs baseline: 1.0754x; 1.0754x over previous
//
#include <hip/hip_runtime.h>
#include <hip/hip_bf16.h>
#include <math.h>

typedef __bf16 bf16;
typedef __bf16 bf16x8 __attribute__((ext_vector_type(8)));
typedef float f32x4 __attribute__((ext_vector_type(4)));

#define MP    4224      // padded token rows (33*128)
#define MACT  4100      // B*N = 4*1025
#define NQTOK 1025
#define NKTOK 1024
#define EDIM  1024
#define FDIM  4096
#define NHEAD 16
#define HD    64
#define QSCALE 0.125f

// flag slots
#define SX    0
#define SY    1
#define SQKVW 2
#define SPW   3
#define SCQW  4
#define SCKVW 5
#define SCPW  6
#define SFC1  7
#define SFC2  8
#define SRPB1 9
#define SRPB2 10
#define S1D   11

// scalar external load, dtype-dispatched
__device__ __forceinline__ float ldx(const void* p, size_t i, bool f32) {
  return f32 ? ((const float*)p)[i] : (float)(((const bf16*)p)[i]);
}
// 8-wide external load -> bf16x8, dtype-dispatched
__device__ __forceinline__ bf16x8 ld8(const void* p, size_t i, bool f32) {
  if (f32) {
    const float* q = (const float*)p + i;
    bf16x8 r;
#pragma unroll
    for (int j = 0; j < 8; ++j) r[j] = (bf16)q[j];
    return r;
  }
  return *(const bf16x8*)((const bf16*)p + i);
}
__device__ __forceinline__ bool getf(const int* flags, int slot) {
  return slot >= 0 && flags[slot] != 0;
}

// ---- per-array dtype probe (cheap insurance; inputs measured fp32) ----
__global__ void dtype_probe_kernel(
    const void* x, const void* y, const void* w0, const void* w1,
    const void* w2, const void* w3, const void* w4, const void* w5,
    const void* w6, const void* r0, const void* r1, const void* oneg,
    int* flags)
{
  __shared__ int bad[11];
  const void* arrs[11] = {x, y, w0, w1, w2, w3, w4, w5, w6, r0, r1};
  const int tid = threadIdx.x;
  if (tid < 11) bad[tid] = 0;
  __syncthreads();
  for (int a = 0; a < 11; ++a) {
    const unsigned short* p = (const unsigned short*)arrs[a];
    int isbad = 0;
#pragma unroll
    for (int j = 0; j < 16; ++j) {
      unsigned short e = p[tid * 16 + j];
      unsigned ex = (e >> 7) & 0xFFu;
      if (ex == 0xFFu || (ex == 0u && (e & 0x7Fu) != 0u)) isbad = 1;
    }
    if (isbad) bad[a] = 1;
  }
  __syncthreads();
  if (tid < 11) flags[tid] = bad[tid];
  if (tid == 11) flags[S1D] = (((const unsigned*)oneg)[0] == 0x3F800000u) ? 1 : 0;
}

// ---------------- zero the pad rows of hln (shared LN-out / attn-out) ----
__global__ void zero_pads_kernel(bf16* hln) {
  int i = blockIdx.x * 256 + threadIdx.x;
  const int n = (MP - MACT) * EDIM;
  if (i < n) hln[(size_t)MACT * EDIM + i] = (bf16)0.0f;
}

// ---------------- LayerNorm (one block per token) ----------------
template<bool FIRST>
__global__ __launch_bounds__(256) void ln_kernel(const void* __restrict__ src,
    float* __restrict__ xf, bf16* __restrict__ out,
    const void* __restrict__ g, const void* __restrict__ bta,
    const int* __restrict__ flags, int sslot) {
  const bool f32s = getf(flags, sslot);
  const bool f32d = getf(flags, S1D);
  const int row = blockIdx.x;
  const int tid = threadIdx.x;
  float v[4];
  if (FIRST) {
#pragma unroll
    for (int i = 0; i < 4; ++i) {
      v[i] = ldx(src, (size_t)row * EDIM + tid + i * 256, f32s);
      xf[(size_t)row * EDIM + tid + i * 256] = v[i];
    }
  } else {
    const float* x = (const float*)src + (size_t)row * EDIM;
#pragma unroll
    for (int i = 0; i < 4; ++i) v[i] = x[tid + i * 256];
  }
  float s = 0.f, sq = 0.f;
#pragma unroll
  for (int i = 0; i < 4; ++i) { s += v[i]; sq += v[i] * v[i]; }
#pragma unroll
  for (int m = 32; m >= 1; m >>= 1) {
    s += __shfl_xor(s, m);
    sq += __shfl_xor(sq, m);
  }
  __shared__ float ss[4], ssq[4];
  const int wave = tid >> 6;
  if ((tid & 63) == 0) { ss[wave] = s; ssq[wave] = sq; }
  __syncthreads();
  s = ss[0] + ss[1] + ss[2] + ss[3];
  sq = ssq[0] + ssq[1] + ssq[2] + ssq[3];
  const float mean = s * (1.f / EDIM);
  const float var = sq * (1.f / EDIM) - mean * mean;
  const float rstd = rsqrtf(var + 1e-5f);
#pragma unroll
  for (int i = 0; i < 4; ++i) {
    int e = tid + i * 256;
    out[(size_t)row * EDIM + e] =
        (bf16)((v[i] - mean) * rstd * ldx(g, e, f32d) + ldx(bta, e, f32d));
  }
}

// ---------------- GEMM: C[m,n] = sum_k A[m,k]*B[n,k], fused epilogues ----
// Split-K: gridDim.z chunks of Kc; atomic epilogues for EPI_Q/RES/FINAL.
enum { EPI_QKV = 0, EPI_KV = 1, EPI_Q = 2, EPI_RES = 3, EPI_GELU = 4, EPI_FINAL = 5 };

template<int EPI>
__global__ __launch_bounds__(256) void gemm_bt(
    const void* __restrict__ A, const void* __restrict__ Bw,
    int Kfull, int Kc, int Nn,
    const void* __restrict__ bias0, const void* __restrict__ bias1,
    const void* __restrict__ gamma, float* __restrict__ xf,
    bf16* __restrict__ out0, bf16* __restrict__ out1, bf16* __restrict__ out2,
    float* __restrict__ outf,
    const int* __restrict__ flags, int aslot, int bslot)
{
  const bool f32a = getf(flags, aslot);
  const bool f32b = getf(flags, bslot);
  const bool f32d = getf(flags, S1D);
  __shared__ bf16 As[128][40];   // pad 32->40: 2-way LDS aliasing only (free)
  __shared__ bf16 Bs[128][40];
  const int tid = threadIdx.x;
  const int lane = tid & 63, wave = tid >> 6;
  const int quad = lane >> 4, l16 = lane & 15;
  const int wr = wave >> 1, wc = wave & 1;
  const int m0 = blockIdx.y * 128, n0 = blockIdx.x * 128;
  const int kz = blockIdx.z;
  const int kbase = kz * Kc;
  const bool first = (kz == 0);
  const int r0 = tid >> 2, c0 = (tid & 3) * 8;

  const size_t arow = (size_t)(m0 + r0);
  const size_t brow = (size_t)(n0 + r0);

  f32x4 acc[4][4];
#pragma unroll
  for (int i = 0; i < 4; ++i)
#pragma unroll
    for (int j = 0; j < 4; ++j)
#pragma unroll
      for (int r = 0; r < 4; ++r) acc[i][j][r] = 0.f;

  for (int k0 = kbase; k0 < kbase + Kc; k0 += 32) {
    *(bf16x8*)(&As[r0][c0])      = ld8(A,  arow * Kfull + k0 + c0,        f32a);
    *(bf16x8*)(&As[r0 + 64][c0]) = ld8(A, (arow + 64) * Kfull + k0 + c0,  f32a);
    *(bf16x8*)(&Bs[r0][c0])      = ld8(Bw, brow * Kfull + k0 + c0,        f32b);
    *(bf16x8*)(&Bs[r0 + 64][c0]) = ld8(Bw, (brow + 64) * Kfull + k0 + c0, f32b);
    __syncthreads();
    bf16x8 af[4], bfv[4];
#pragma unroll
    for (int i = 0; i < 4; ++i) {
      af[i]  = *(const bf16x8*)(&As[wr * 64 + i * 16 + l16][quad * 8]);
      bfv[i] = *(const bf16x8*)(&Bs[wc * 64 + i * 16 + l16][quad * 8]);
    }
#pragma unroll
    for (int mb = 0; mb < 4; ++mb)
#pragma unroll
      for (int nb = 0; nb < 4; ++nb)
        acc[mb][nb] = __builtin_amdgcn_mfma_f32_16x16x32_bf16(af[mb], bfv[nb], acc[mb][nb], 0, 0, 0);
    __syncthreads();
  }

  // epilogue: C element (mb,nb,r): gm row, gn col
#pragma unroll
  for (int mb = 0; mb < 4; ++mb) {
#pragma unroll
    for (int r = 0; r < 4; ++r) {
      const int gm = m0 + wr * 64 + mb * 16 + quad * 4 + r;
#pragma unroll
      for (int nb = 0; nb < 4; ++nb) {
        const int gn = n0 + wc * 64 + nb * 16 + l16;
        float v = acc[mb][nb][r];
        if (EPI == EPI_QKV) {
          if (gm < MACT) {
            unsigned b = (unsigned)gm / 1025u;
            unsigned t = (unsigned)gm - b * 1025u;
            int sec = gn >> 10, e = gn & 1023;
            int h = e >> 6, d = e & 63;
            size_t o = ((size_t)(b * NHEAD + h) * NQTOK + t) * HD + d;
            if (sec == 0)      out0[o] = (bf16)((v + ldx(bias0, e, f32d)) * QSCALE);
            else if (sec == 1) out1[o] = (bf16)v;
            else               out2[o] = (bf16)(v + ldx(bias1, e, f32d));
          }
        } else if (EPI == EPI_KV) {
          unsigned b = (unsigned)gm >> 10;
          unsigned t = (unsigned)gm & 1023u;
          int sec = gn >> 10, e = gn & 1023;
          int h = e >> 6, d = e & 63;
          size_t o = ((size_t)(b * NHEAD + h) * NKTOK + t) * HD + d;
          if (sec == 0) out0[o] = (bf16)v;
          else          out1[o] = (bf16)(v + ldx(bias1, e, f32d));
        } else if (EPI == EPI_Q) {
          // split-K: fp32 Q scratch (aliases d_out), zeroed before launch
          if (gm < MACT) {
            unsigned b = (unsigned)gm / 1025u;
            unsigned t = (unsigned)gm - b * 1025u;
            int h = gn >> 6, d = gn & 63;
            float add = (v + (first ? ldx(bias0, gn, f32d) : 0.f)) * QSCALE;
            atomicAdd(&outf[((size_t)(b * NHEAD + h) * NQTOK + t) * HD + d], add);
          }
        } else if (EPI == EPI_RES) {
          if (gm < MACT) {
            size_t o = (size_t)gm * EDIM + gn;
            float add = ldx(gamma, gn, f32d) * (v + (first ? ldx(bias0, gn, f32d) : 0.f));
            atomicAdd(&xf[o], add);
          }
        } else if (EPI == EPI_GELU) {
          float z = v + ldx(bias0, gn, f32d);
          float ge = 0.5f * z * (1.0f + erff(z * 0.70710678118f));
          out0[(size_t)gm * Nn + gn] = (bf16)ge;
        } else { // EPI_FINAL: d_out (f32) zeroed before launch; split-K atomics
          if (gm < MACT) {
            size_t o = (size_t)gm * EDIM + gn;
            float add = ldx(gamma, gn, f32d) * (v + (first ? ldx(bias0, gn, f32d) : 0.f));
            if (first) add += xf[o];
            atomicAdd(&outf[o], add);
          }
        }
      }
    }
  }
}

// ---------------- Flash attention (self: causal+rpb, cross: rpb) --------
// grid (17, H, B), block 256 = 4 waves; 64-query tile, 64-key chunks.
// CROSS: Q is fp32 (split-K scratch); self: Q is bf16.
template<bool CROSS>
__global__ __launch_bounds__(256) void attn_kernel(
    const void* __restrict__ Q, const bf16* __restrict__ Kg,
    const bf16* __restrict__ Vg, const void* __restrict__ rpb,
    bf16* __restrict__ out, const int* __restrict__ flags, int rslot)
{
  const bool f32r = getf(flags, rslot);
  const int NK  = CROSS ? NKTOK : NQTOK;
  const int NRD = CROSS ? 3970 : 3972;
  const int qt = blockIdx.x, h = blockIdx.y, b = blockIdx.z;
  const int tid = threadIdx.x;
  const int lane = tid & 63, wave = tid >> 6;
  const int quad = lane >> 4, l16 = lane & 15;

  __shared__ float rpb_s[4096];
  __shared__ bf16 Ks[64][72];
  __shared__ bf16 Vs[64][72];
  __shared__ bf16 Ps[4][16][72];

  for (int i = tid; i < 4096; i += 256)
    rpb_s[i] = (i < NRD) ? ldx(rpb, (size_t)i * NHEAD + h, f32r) : 0.f;

  const int q0 = qt * 64;
  const int qrow = q0 + wave * 16 + l16;
  const size_t qhb = (size_t)(b * NHEAD + h) * NQTOK;
  bf16x8 qf0, qf1;
  if (qrow < NQTOK) {
    if (CROSS) {
      const float* Qf = (const float*)Q + (qhb + qrow) * HD;
#pragma unroll
      for (int j = 0; j < 8; ++j) {
        qf0[j] = (bf16)Qf[quad * 8 + j];
        qf1[j] = (bf16)Qf[32 + quad * 8 + j];
      }
    } else {
      const bf16* Qb = (const bf16*)Q;
      qf0 = *(const bf16x8*)(Qb + (qhb + qrow) * HD + quad * 8);
      qf1 = *(const bf16x8*)(Qb + (qhb + qrow) * HD + 32 + quad * 8);
    }
  } else {
#pragma unroll
    for (int j = 0; j < 8; ++j) { qf0[j] = (bf16)0.f; qf1[j] = (bf16)0.f; }
  }

  float m_run[4], l_run[4];
  f32x4 oacc[4];
#pragma unroll
  for (int r = 0; r < 4; ++r) { m_run[r] = -1e30f; l_run[r] = 0.f; }
#pragma unroll
  for (int d = 0; d < 4; ++d)
#pragma unroll
    for (int r = 0; r < 4; ++r) oacc[d][r] = 0.f;

  const size_t kvb = (size_t)(b * NHEAD + h) * NK;
  const int nch = CROSS ? (NKTOK / 64) : (qt + 1);  // causal chunk skipping

  for (int c = 0; c < nch; ++c) {
    const int kc = c * 64;
    __syncthreads();   // protect Ks/Vs (and first-iter rpb_s) reuse
#pragma unroll
    for (int vv = 0; vv < 2; ++vv) {
      int vi = tid + vv * 256;
      int rr = vi >> 3, co = (vi & 7) * 8;
      int krow = kc + rr;
      bf16x8 k8, v8;
      if (!CROSS && krow >= NK) {
#pragma unroll
        for (int j = 0; j < 8; ++j) { k8[j] = (bf16)0.f; v8[j] = (bf16)0.f; }
      } else {
        k8 = *(const bf16x8*)(Kg + (kvb + krow) * HD + co);
        v8 = *(const bf16x8*)(Vg + (kvb + krow) * HD + co);
      }
      *(bf16x8*)(&Ks[rr][co]) = k8;
      *(bf16x8*)(&Vs[rr][co]) = v8;
    }
    __syncthreads();

    // ---- S = Q K^T + bias (+causal) ----
    float sv[4][4];
#pragma unroll
    for (int kb = 0; kb < 4; ++kb) {
      f32x4 a;
#pragma unroll
      for (int r = 0; r < 4; ++r) a[r] = 0.f;
      bf16x8 kf0 = *(const bf16x8*)(&Ks[kb * 16 + l16][quad * 8]);
      bf16x8 kf1 = *(const bf16x8*)(&Ks[kb * 16 + l16][32 + quad * 8]);
      a = __builtin_amdgcn_mfma_f32_16x16x32_bf16(qf0, kf0, a, 0, 0, 0);
      a = __builtin_amdgcn_mfma_f32_16x16x32_bf16(qf1, kf1, a, 0, 0, 0);
      const int kg = kc + kb * 16 + l16;
#pragma unroll
      for (int r = 0; r < 4; ++r) {
        const int qg = q0 + wave * 16 + quad * 4 + r;
        bool valid = (kg < NK) && (CROSS || kg <= qg);
        int idx;
        if (CROSS) {
          if (qg == 0) idx = 3969;
          else {
            int p = qg - 1;
            int dr = (p >> 5) - (kg >> 5);
            int dc = (p & 31) - (kg & 31);
            idx = (dr + 31) * 63 + (dc + 31);
          }
        } else {
          if (qg == 0 && kg == 0) idx = 3971;
          else if (qg == 0) idx = 3969;
          else if (kg == 0) idx = 3970;
          else {
            int p = qg - 1, sk = kg - 1;
            int dr = (p >> 5) - (sk >> 5);
            int dc = (p & 31) - (sk & 31);
            idx = (dr + 31) * 63 + (dc + 31);
          }
        }
        idx = idx < 0 ? 0 : (idx > 4095 ? 4095 : idx);
        sv[kb][r] = valid ? (a[r] + rpb_s[idx]) : -1e30f;
      }
    }

    // ---- online softmax (row stats live in the 16 lanes of each quad) ----
#pragma unroll
    for (int r = 0; r < 4; ++r) {
      float mx = fmaxf(fmaxf(sv[0][r], sv[1][r]), fmaxf(sv[2][r], sv[3][r]));
#pragma unroll
      for (int mk = 8; mk >= 1; mk >>= 1) mx = fmaxf(mx, __shfl_xor(mx, mk));
      const float mnew = fmaxf(m_run[r], mx);
      const float alpha = __expf(m_run[r] - mnew);
      m_run[r] = mnew;
      float rs = 0.f;
#pragma unroll
      for (int kb = 0; kb < 4; ++kb) {
        float p = __expf(sv[kb][r] - mnew);
        rs += p;
        Ps[wave][quad * 4 + r][kb * 16 + l16] = (bf16)p;
      }
#pragma unroll
      for (int mk = 8; mk >= 1; mk >>= 1) rs += __shfl_xor(rs, mk);
      l_run[r] = l_run[r] * alpha + rs;
#pragma unroll
      for (int d = 0; d < 4; ++d) oacc[d][r] *= alpha;
    }

    // Drain the Ps ds_writes before the cross-lane A-layout reads.
    __syncthreads();

    // ---- O += P V  (P via per-wave LDS round-trip into A-layout) ----
    bf16x8 pf0 = *(const bf16x8*)(&Ps[wave][l16][quad * 8]);
    bf16x8 pf1 = *(const bf16x8*)(&Ps[wave][l16][32 + quad * 8]);
#pragma unroll
    for (int db = 0; db < 4; ++db) {
      bf16x8 vf0, vf1;
#pragma unroll
      for (int j = 0; j < 8; ++j) {
        vf0[j] = Vs[quad * 8 + j][db * 16 + l16];
        vf1[j] = Vs[32 + quad * 8 + j][db * 16 + l16];
      }
      oacc[db] = __builtin_amdgcn_mfma_f32_16x16x32_bf16(pf0, vf0, oacc[db], 0, 0, 0);
      oacc[db] = __builtin_amdgcn_mfma_f32_16x16x32_bf16(pf1, vf1, oacc[db], 0, 0, 0);
    }
  }

  // ---- write O ----
#pragma unroll
  for (int r = 0; r < 4; ++r) {
    const int qg = q0 + wave * 16 + quad * 4 + r;
    if (qg < NQTOK) {
      const float inv = 1.f / l_run[r];
      const size_t row = (size_t)b * NQTOK + qg;
#pragma unroll
      for (int db = 0; db < 4; ++db)
        out[row * EDIM + h * HD + db * 16 + l16] = (bf16)(oacc[db][r] * inv);
    }
  }
}

// ---------------- launch ----------------
extern "C" void kernel_launch(void* const* d_in, const int* in_sizes, int n_in,
                              void* d_out, int out_size, void* d_ws, size_t ws_size,
                              hipStream_t stream) {
  (void)in_sizes; (void)n_in; (void)out_size; (void)ws_size;
  const void* x        = d_in[0];
  const void* y        = d_in[1];
  const void* n1g      = d_in[2];
  const void* n1b      = d_in[3];
  const void* n2g      = d_in[4];
  const void* n2b      = d_in[5];
  const void* n3g      = d_in[6];
  const void* n3b      = d_in[7];
  const void* sa_qkv_w = d_in[8];
  const void* sa_qb    = d_in[9];
  const void* sa_vb    = d_in[10];
  const void* sa_rpb   = d_in[11];
  const void* sa_pw    = d_in[12];
  const void* sa_pb    = d_in[13];
  const void* ca_qw    = d_in[14];
  const void* ca_kvw   = d_in[15];
  const void* ca_qb    = d_in[16];
  const void* ca_vb    = d_in[17];
  const void* ca_rpb   = d_in[18];
  const void* ca_pw    = d_in[19];
  const void* ca_pb    = d_in[20];
  const void* fc1_w    = d_in[21];
  const void* fc1_b    = d_in[22];
  const void* fc2_w    = d_in[23];
  const void* fc2_b    = d_in[24];
  const void* g1       = d_in[25];
  const void* g2       = d_in[26];
  const void* g3       = d_in[27];
  float* outf = (float*)d_out;     // reference output dtype is float32
  // Cross-attn fp32 Q scratch aliases d_out: 4*16*1025*64 = 4100*1024 floats.
  float* qtf = (float*)d_out;

  // Workspace layout (~60.6 MB):
  //   flags : int[64] dtype flags
  //   xf    : fp32 residual, MP*EDIM*4            (16.9 MB)
  //   hln   : LN-out / attn-out bf16, MP*EDIM*2   ( 8.7 MB)
  //   h1    : FFN hidden bf16, MP*FDIM*2          (34.6 MB)  [qt/kt/vt alias head]
  char* w = (char*)d_ws;
  int* flags = (int*)w;   w += 256;
  float* xf = (float*)w;  w += (size_t)MP * EDIM * 4;
  bf16* hln = (bf16*)w;   w += (size_t)MP * EDIM * 2;
  char* big = w;          // MP*FDIM*2 = 34.6 MB reserved
  const size_t qkv_sz = (size_t)4 * NHEAD * NQTOK * HD * 2;  // 8.4 MB
  bf16* qt = (bf16*)big;
  bf16* kt = (bf16*)(big + qkv_sz);
  bf16* vt = (bf16*)(big + 2 * qkv_sz);
  bf16* h1 = (bf16*)big;          // aliases qt/kt/vt (dead by FFN)

  dtype_probe_kernel<<<1, 256, 0, stream>>>(
      x, y, sa_qkv_w, sa_pw, ca_qw, ca_kvw, ca_pw, fc1_w, fc2_w,
      sa_rpb, ca_rpb, n1g, flags);
  zero_pads_kernel<<<dim3(((MP - MACT) * EDIM + 255) / 256), 256, 0, stream>>>(hln);
  // zero the fp32 Q scratch (d_out) for split-K atomic accumulation
  hipMemsetAsync(qtf, 0, (size_t)MACT * EDIM * 4, stream);

  // --- self-attention block ---
  ln_kernel<true><<<MACT, 256, 0, stream>>>(x, xf, hln, n1g, n1b, flags, SX);
  gemm_bt<EPI_QKV><<<dim3(24, 33, 1), 256, 0, stream>>>(hln, sa_qkv_w, 1024, 1024, 3072,
      sa_qb, sa_vb, nullptr, nullptr, qt, kt, vt, nullptr, flags, -1, SQKVW);
  attn_kernel<false><<<dim3(17, NHEAD, 4), 256, 0, stream>>>(qt, kt, vt, sa_rpb, hln, flags, SRPB1);
  gemm_bt<EPI_RES><<<dim3(8, 33, 2), 256, 0, stream>>>(hln, sa_pw, 1024, 512, 1024,
      sa_pb, nullptr, g1, xf, nullptr, nullptr, nullptr, nullptr, flags, -1, SPW);

  // --- cross-attention block ---
  ln_kernel<false><<<MACT, 256, 0, stream>>>(xf, nullptr, hln, n2g, n2b, flags, -1);
  gemm_bt<EPI_Q><<<dim3(8, 33, 2), 256, 0, stream>>>(hln, ca_qw, 1024, 512, 1024,
      ca_qb, nullptr, nullptr, nullptr, nullptr, nullptr, nullptr, qtf, flags, -1, SCQW);
  gemm_bt<EPI_KV><<<dim3(16, 32, 1), 256, 0, stream>>>(y, ca_kvw, 1024, 1024, 2048,
      nullptr, ca_vb, nullptr, nullptr, kt, vt, nullptr, nullptr, flags, SY, SCKVW);
  attn_kernel<true><<<dim3(17, NHEAD, 4), 256, 0, stream>>>(qtf, kt, vt, ca_rpb, hln, flags, SRPB2);
  gemm_bt<EPI_RES><<<dim3(8, 33, 2), 256, 0, stream>>>(hln, ca_pw, 1024, 512, 1024,
      ca_pb, nullptr, g2, xf, nullptr, nullptr, nullptr, nullptr, flags, -1, SCPW);

  // --- FFN ---
  ln_kernel<false><<<MACT, 256, 0, stream>>>(xf, nullptr, hln, n3g, n3b, flags, -1);
  gemm_bt<EPI_GELU><<<dim3(32, 33, 1), 256, 0, stream>>>(hln, fc1_w, 1024, 1024, 4096,
      fc1_b, nullptr, nullptr, nullptr, h1, nullptr, nullptr, nullptr, flags, -1, SFC1);
  // d_out served as Q scratch; re-zero it for the final split-K accumulation
  hipMemsetAsync(outf, 0, (size_t)MACT * EDIM * 4, stream);
  gemm_bt<EPI_FINAL><<<dim3(8, 33, 4), 256, 0, stream>>>(h1, fc2_w, 4096, 1024, 1024,
      fc2_b, nullptr, g3, xf, nullptr, nullptr, nullptr, outf, flags, -1, SFC2);
}

// Round 7
// 939.415 us; speedup vs baseline: 1.4860x; 1.3817x over previous
//
#include <hip/hip_runtime.h>
#include <hip/hip_bf16.h>
#include <math.h>

typedef __bf16 bf16;
typedef __bf16 bf16x8 __attribute__((ext_vector_type(8)));
typedef float f32x4 __attribute__((ext_vector_type(4)));

#define MP    4224      // padded token rows (33*128)
#define MACT  4100      // B*N = 4*1025
#define NQTOK 1025
#define NKTOK 1024
#define EDIM  1024
#define FDIM  4096
#define NHEAD 16
#define HD    64
#define QSCALE 0.125f

// ---- async global->LDS, 16B per lane; LDS base must be wave-uniform ----
__device__ __forceinline__ void glds16(const bf16* g, bf16* l) {
  __builtin_amdgcn_global_load_lds(
      (const __attribute__((address_space(1))) void*)g,
      (__attribute__((address_space(3))) void*)l, 16, 0, 0);
}

// scalar / 8-wide fp32->bf16 loads (fallback + conversion paths)
__device__ __forceinline__ bf16x8 ld8(const void* p, size_t i, bool f32) {
  if (f32) {
    const float* q = (const float*)p + i;
    bf16x8 r;
#pragma unroll
    for (int j = 0; j < 8; ++j) r[j] = (bf16)q[j];
    return r;
  }
  return *(const bf16x8*)((const bf16*)p + i);
}

// ---- weight/y fp32 -> bf16 pool conversion (one pass per launch) ----
struct WPtrs { const float* s[8]; };
__global__ __launch_bounds__(256) void conv_kernel(WPtrs wp, bf16* dst) {
  const size_t sz[8] = {3145728UL, 1048576UL, 1048576UL, 2097152UL,
                        1048576UL, 4194304UL, 4194304UL, 4194304UL};
  size_t id = ((size_t)blockIdx.x * 256 + threadIdx.x) * 8;
  size_t off = 0;
#pragma unroll
  for (int i = 0; i < 8; ++i) {
    if (id < off + sz[i]) {
      const float* s = wp.s[i] + (id - off);
      bf16x8 r;
#pragma unroll
      for (int j = 0; j < 8; ++j) r[j] = (bf16)s[j];
      *(bf16x8*)(dst + id) = r;
      return;
    }
    off += sz[i];
  }
}

// ---------------- zero the pad rows of hln ----------------
__global__ void zero_pads_kernel(bf16* hln) {
  int i = blockIdx.x * 256 + threadIdx.x;
  const int n = (MP - MACT) * EDIM;
  if (i < n) hln[(size_t)MACT * EDIM + i] = (bf16)0.0f;
}

// ---------------- LayerNorm (one block per token) ----------------
template<bool FIRST>
__global__ __launch_bounds__(256) void ln_kernel(const float* __restrict__ src,
    float* __restrict__ xf, bf16* __restrict__ out,
    const float* __restrict__ g, const float* __restrict__ bta) {
  const int row = blockIdx.x;
  const int tid = threadIdx.x;
  float v[4];
#pragma unroll
  for (int i = 0; i < 4; ++i) {
    v[i] = src[(size_t)row * EDIM + tid + i * 256];
    if (FIRST) xf[(size_t)row * EDIM + tid + i * 256] = v[i];
  }
  float s = 0.f, sq = 0.f;
#pragma unroll
  for (int i = 0; i < 4; ++i) { s += v[i]; sq += v[i] * v[i]; }
#pragma unroll
  for (int m = 32; m >= 1; m >>= 1) {
    s += __shfl_xor(s, m);
    sq += __shfl_xor(sq, m);
  }
  __shared__ float ss[4], ssq[4];
  const int wave = tid >> 6;
  if ((tid & 63) == 0) { ss[wave] = s; ssq[wave] = sq; }
  __syncthreads();
  s = ss[0] + ss[1] + ss[2] + ss[3];
  sq = ssq[0] + ssq[1] + ssq[2] + ssq[3];
  const float mean = s * (1.f / EDIM);
  const float var = sq * (1.f / EDIM) - mean * mean;
  const float rstd = rsqrtf(var + 1e-5f);
#pragma unroll
  for (int i = 0; i < 4; ++i) {
    int e = tid + i * 256;
    out[(size_t)row * EDIM + e] = (bf16)((v[i] - mean) * rstd * g[e] + bta[e]);
  }
}

// ---------------- GEMM: C[m,n] = sum_k A[m,k]*B[n,k], fused epilogues ----
// ASY: A,B bf16, m97-style global_load_lds staging. split-K via blockIdx.z.
enum { EPI_QKV = 0, EPI_KV = 1, EPI_Q = 2, EPI_RES = 3, EPI_GELU = 4, EPI_FINAL = 5 };

template<int EPI, bool ASY>
__global__ __launch_bounds__(256) void gemm_bt(
    const void* __restrict__ A, const void* __restrict__ Bw,
    int K, int Kc,
    const float* __restrict__ bias0, const float* __restrict__ bias1,
    const float* __restrict__ gamma, float* __restrict__ xf,
    bf16* __restrict__ out0, bf16* __restrict__ out1, bf16* __restrict__ out2,
    float* __restrict__ outf)
{
  constexpr int LDP = ASY ? 32 : 40;   // async needs contiguous rows (no pad)
  __shared__ bf16 As[128][LDP];
  __shared__ bf16 Bs[128][LDP];
  const int tid = threadIdx.x;
  const int lane = tid & 63, wave = tid >> 6;
  const int quad = lane >> 4, l16 = lane & 15;
  const int wr = wave >> 1, wc = wave & 1;
  const int m0 = blockIdx.y * 128, n0 = blockIdx.x * 128;
  const int kbase = blockIdx.z * Kc;
  const bool first = (blockIdx.z == 0);
  const int r0 = tid >> 2, c0 = (tid & 3) * 8;

  const bf16* gA = nullptr; const bf16* gB = nullptr;
  bf16* lA = nullptr; bf16* lB = nullptr;
  if (ASY) {
    gA = (const bf16*)A + (size_t)(m0 + wave * 16 + (lane >> 2)) * K + kbase + (lane & 3) * 8;
    gB = (const bf16*)Bw + (size_t)(n0 + wave * 16 + (lane >> 2)) * K + kbase + (lane & 3) * 8;
    lA = &As[wave * 16][0];
    lB = &Bs[wave * 16][0];
  }

  f32x4 acc[4][4];
#pragma unroll
  for (int i = 0; i < 4; ++i)
#pragma unroll
    for (int j = 0; j < 4; ++j)
#pragma unroll
      for (int r = 0; r < 4; ++r) acc[i][j][r] = 0.f;

  for (int k0 = 0; k0 < Kc; k0 += 32) {
    if (ASY) {
      glds16(gA, lA);
      glds16(gA + (size_t)64 * K, lA + 64 * 32);
      glds16(gB, lB);
      glds16(gB + (size_t)64 * K, lB + 64 * 32);
      gA += 32; gB += 32;
    } else {
      const bool f32a = (EPI == EPI_KV);   // fallback: y fp32, weights fp32
      const size_t kk = (size_t)(kbase + k0);
      *(bf16x8*)(&As[r0][c0])      = ld8(A,  (size_t)(m0 + r0) * K + kk + c0, f32a);
      *(bf16x8*)(&As[r0 + 64][c0]) = ld8(A,  (size_t)(m0 + r0 + 64) * K + kk + c0, f32a);
      *(bf16x8*)(&Bs[r0][c0])      = ld8(Bw, (size_t)(n0 + r0) * K + kk + c0, true);
      *(bf16x8*)(&Bs[r0 + 64][c0]) = ld8(Bw, (size_t)(n0 + r0 + 64) * K + kk + c0, true);
    }
    __syncthreads();
    bf16x8 af[4], bfv[4];
#pragma unroll
    for (int i = 0; i < 4; ++i) {
      af[i]  = *(const bf16x8*)(&As[wr * 64 + i * 16 + l16][quad * 8]);
      bfv[i] = *(const bf16x8*)(&Bs[wc * 64 + i * 16 + l16][quad * 8]);
    }
#pragma unroll
    for (int mb = 0; mb < 4; ++mb)
#pragma unroll
      for (int nb = 0; nb < 4; ++nb)
        acc[mb][nb] = __builtin_amdgcn_mfma_f32_16x16x32_bf16(af[mb], bfv[nb], acc[mb][nb], 0, 0, 0);
    __syncthreads();
  }

  // epilogue
#pragma unroll
  for (int mb = 0; mb < 4; ++mb) {
#pragma unroll
    for (int r = 0; r < 4; ++r) {
      const int gm = m0 + wr * 64 + mb * 16 + quad * 4 + r;
#pragma unroll
      for (int nb = 0; nb < 4; ++nb) {
        const int gn = n0 + wc * 64 + nb * 16 + l16;
        float v = acc[mb][nb][r];
        if (EPI == EPI_QKV) {
          if (gm < MACT) {
            unsigned b = (unsigned)gm / 1025u;
            unsigned t = (unsigned)gm - b * 1025u;
            int sec = gn >> 10, e = gn & 1023;
            int h = e >> 6, d = e & 63;
            size_t o = ((size_t)(b * NHEAD + h) * NQTOK + t) * HD + d;
            if (sec == 0)      out0[o] = (bf16)((v + bias0[e]) * QSCALE);
            else if (sec == 1) out1[o] = (bf16)v;
            else               out2[o] = (bf16)(v + bias1[e]);
          }
        } else if (EPI == EPI_KV) {
          unsigned b = (unsigned)gm >> 10;
          unsigned t = (unsigned)gm & 1023u;
          int sec = gn >> 10, e = gn & 1023;
          int h = e >> 6, d = e & 63;
          size_t o = ((size_t)(b * NHEAD + h) * NKTOK + t) * HD + d;
          if (sec == 0) out0[o] = (bf16)v;
          else          out1[o] = (bf16)(v + bias1[e]);
        } else if (EPI == EPI_Q) {
          if (gm < MACT) {
            unsigned b = (unsigned)gm / 1025u;
            unsigned t = (unsigned)gm - b * 1025u;
            int h = gn >> 6, d = gn & 63;
            float add = (v + (first ? bias0[gn] : 0.f)) * QSCALE;
            atomicAdd(&outf[((size_t)(b * NHEAD + h) * NQTOK + t) * HD + d], add);
          }
        } else if (EPI == EPI_RES) {
          if (gm < MACT) {
            float add = gamma[gn] * (v + (first ? bias0[gn] : 0.f));
            atomicAdd(&xf[(size_t)gm * EDIM + gn], add);
          }
        } else if (EPI == EPI_GELU) {
          float z = v + bias0[gn];
          float ge = 0.5f * z * (1.0f + erff(z * 0.70710678118f));
          out0[(size_t)gm * FDIM + gn] = (bf16)ge;
        } else { // EPI_FINAL: d_out f32, zeroed before launch
          if (gm < MACT) {
            size_t o = (size_t)gm * EDIM + gn;
            float add = gamma[gn] * (v + (first ? bias0[gn] : 0.f));
            if (first) add += xf[o];
            atomicAdd(&outf[o], add);
          }
        }
      }
    }
  }
}

// ---------------- Flash attention (self: causal+rpb, cross: rpb) --------
// grid (17, H, B), block 256 = 4 waves; 64-query tile, 64-key chunks.
// V staged TRANSPOSED (Vt[d][key]) so PV B-fragments are ds_read_b128.
template<bool CROSS>
__global__ __launch_bounds__(256) void attn_kernel(
    const void* __restrict__ Q, const bf16* __restrict__ Kg,
    const bf16* __restrict__ Vg, const float* __restrict__ rpb,
    bf16* __restrict__ out)
{
  const int NK  = CROSS ? NKTOK : NQTOK;
  const int NRD = CROSS ? 3970 : 3972;
  const int qt = blockIdx.x, h = blockIdx.y, b = blockIdx.z;
  const int tid = threadIdx.x;
  const int lane = tid & 63, wave = tid >> 6;
  const int quad = lane >> 4, l16 = lane & 15;

  __shared__ bf16 rpb_s[4096];       // bf16: bias |err| ~1e-4, negligible
  __shared__ bf16 Ks[64][72];
  __shared__ bf16 Vt[64][72];        // V transposed: [d][key]
  __shared__ bf16 Ps[4][16][72];     // per-wave P round-trip

  for (int i = tid; i < 4096; i += 256)
    rpb_s[i] = (bf16)((i < NRD) ? rpb[(size_t)i * NHEAD + h] : 0.f);

  const int q0 = qt * 64;
  const int qrow = q0 + wave * 16 + l16;
  const size_t qhb = (size_t)(b * NHEAD + h) * NQTOK;
  bf16x8 qf0, qf1;
  if (qrow < NQTOK) {
    if (CROSS) {
      const float* Qf = (const float*)Q + (qhb + qrow) * HD;
#pragma unroll
      for (int j = 0; j < 8; ++j) {
        qf0[j] = (bf16)Qf[quad * 8 + j];
        qf1[j] = (bf16)Qf[32 + quad * 8 + j];
      }
    } else {
      const bf16* Qb = (const bf16*)Q;
      qf0 = *(const bf16x8*)(Qb + (qhb + qrow) * HD + quad * 8);
      qf1 = *(const bf16x8*)(Qb + (qhb + qrow) * HD + 32 + quad * 8);
    }
  } else {
#pragma unroll
    for (int j = 0; j < 8; ++j) { qf0[j] = (bf16)0.f; qf1[j] = (bf16)0.f; }
  }

  float m_run[4], l_run[4];
  f32x4 oacc[4];
#pragma unroll
  for (int r = 0; r < 4; ++r) { m_run[r] = -1e30f; l_run[r] = 0.f; }
#pragma unroll
  for (int d = 0; d < 4; ++d)
#pragma unroll
    for (int r = 0; r < 4; ++r) oacc[d][r] = 0.f;

  const size_t kvb = (size_t)(b * NHEAD + h) * NK;
  const int nch = CROSS ? (NKTOK / 64) : (qt + 1);  // causal chunk skipping

  for (int c = 0; c < nch; ++c) {
    const int kc = c * 64;
    if (c) __syncthreads();    // all waves done with prev Ks/Vt
#pragma unroll
    for (int vv = 0; vv < 2; ++vv) {
      int vi = tid + vv * 256;
      int rr = vi >> 3, co = (vi & 7) * 8;
      int krow = kc + rr;
      bf16x8 k8, v8;
      if (!CROSS && krow >= NK) {
#pragma unroll
        for (int j = 0; j < 8; ++j) { k8[j] = (bf16)0.f; v8[j] = (bf16)0.f; }
      } else {
        k8 = *(const bf16x8*)(Kg + (kvb + krow) * HD + co);
        v8 = *(const bf16x8*)(Vg + (kvb + krow) * HD + co);
      }
      *(bf16x8*)(&Ks[rr][co]) = k8;
#pragma unroll
      for (int j = 0; j < 8; ++j) Vt[co + j][rr] = v8[j];   // transpose scatter
    }
    __syncthreads();

    // ---- S = Q K^T + bias (+causal) ----
    float sv[4][4];
#pragma unroll
    for (int kb = 0; kb < 4; ++kb) {
      f32x4 a;
#pragma unroll
      for (int r = 0; r < 4; ++r) a[r] = 0.f;
      bf16x8 kf0 = *(const bf16x8*)(&Ks[kb * 16 + l16][quad * 8]);
      bf16x8 kf1 = *(const bf16x8*)(&Ks[kb * 16 + l16][32 + quad * 8]);
      a = __builtin_amdgcn_mfma_f32_16x16x32_bf16(qf0, kf0, a, 0, 0, 0);
      a = __builtin_amdgcn_mfma_f32_16x16x32_bf16(qf1, kf1, a, 0, 0, 0);
      const int kg = kc + kb * 16 + l16;
#pragma unroll
      for (int r = 0; r < 4; ++r) {
        const int qg = q0 + wave * 16 + quad * 4 + r;
        bool valid = (kg < NK) && (CROSS || kg <= qg);
        int idx;
        if (CROSS) {
          if (qg == 0) idx = 3969;
          else {
            int p = qg - 1;
            int dr = (p >> 5) - (kg >> 5);
            int dc = (p & 31) - (kg & 31);
            idx = (dr + 31) * 63 + (dc + 31);
          }
        } else {
          if (qg == 0 && kg == 0) idx = 3971;
          else if (qg == 0) idx = 3969;
          else if (kg == 0) idx = 3970;
          else {
            int p = qg - 1, sk = kg - 1;
            int dr = (p >> 5) - (sk >> 5);
            int dc = (p & 31) - (sk & 31);
            idx = (dr + 31) * 63 + (dc + 31);
          }
        }
        idx = idx < 0 ? 0 : (idx > 4095 ? 4095 : idx);
        sv[kb][r] = valid ? (a[r] + (float)rpb_s[idx]) : -1e30f;
      }
    }

    // ---- online softmax ----
#pragma unroll
    for (int r = 0; r < 4; ++r) {
      float mx = fmaxf(fmaxf(sv[0][r], sv[1][r]), fmaxf(sv[2][r], sv[3][r]));
#pragma unroll
      for (int mk = 8; mk >= 1; mk >>= 1) mx = fmaxf(mx, __shfl_xor(mx, mk));
      const float mnew = fmaxf(m_run[r], mx);
      const float alpha = __expf(m_run[r] - mnew);
      m_run[r] = mnew;
      float rs = 0.f;
#pragma unroll
      for (int kb = 0; kb < 4; ++kb) {
        float p = __expf(sv[kb][r] - mnew);
        rs += p;
        Ps[wave][quad * 4 + r][kb * 16 + l16] = (bf16)p;
      }
#pragma unroll
      for (int mk = 8; mk >= 1; mk >>= 1) rs += __shfl_xor(rs, mk);
      l_run[r] = l_run[r] * alpha + rs;
#pragma unroll
      for (int d = 0; d < 4; ++d) oacc[d][r] *= alpha;
    }

    // Ps round-trip is intra-wave; compiler orders same-array DS ops (no barrier)

    // ---- O += P V ----
    bf16x8 pf0 = *(const bf16x8*)(&Ps[wave][l16][quad * 8]);
    bf16x8 pf1 = *(const bf16x8*)(&Ps[wave][l16][32 + quad * 8]);
#pragma unroll
    for (int db = 0; db < 4; ++db) {
      bf16x8 vf0 = *(const bf16x8*)(&Vt[db * 16 + l16][quad * 8]);
      bf16x8 vf1 = *(const bf16x8*)(&Vt[db * 16 + l16][32 + quad * 8]);
      oacc[db] = __builtin_amdgcn_mfma_f32_16x16x32_bf16(pf0, vf0, oacc[db], 0, 0, 0);
      oacc[db] = __builtin_amdgcn_mfma_f32_16x16x32_bf16(pf1, vf1, oacc[db], 0, 0, 0);
    }
  }

  // ---- write O ----
#pragma unroll
  for (int r = 0; r < 4; ++r) {
    const int qg = q0 + wave * 16 + quad * 4 + r;
    if (qg < NQTOK) {
      const float inv = 1.f / l_run[r];
      const size_t row = (size_t)b * NQTOK + qg;
#pragma unroll
      for (int db = 0; db < 4; ++db)
        out[row * EDIM + h * HD + db * 16 + l16] = (bf16)(oacc[db][r] * inv);
    }
  }
}

// ---------------- launch ----------------
extern "C" void kernel_launch(void* const* d_in, const int* in_sizes, int n_in,
                              void* d_out, int out_size, void* d_ws, size_t ws_size,
                              hipStream_t stream) {
  (void)in_sizes; (void)n_in; (void)out_size;
  const float* x        = (const float*)d_in[0];
  const float* y        = (const float*)d_in[1];
  const float* n1g      = (const float*)d_in[2];
  const float* n1b      = (const float*)d_in[3];
  const float* n2g      = (const float*)d_in[4];
  const float* n2b      = (const float*)d_in[5];
  const float* n3g      = (const float*)d_in[6];
  const float* n3b      = (const float*)d_in[7];
  const float* sa_qkv_w = (const float*)d_in[8];
  const float* sa_qb    = (const float*)d_in[9];
  const float* sa_vb    = (const float*)d_in[10];
  const float* sa_rpb   = (const float*)d_in[11];
  const float* sa_pw    = (const float*)d_in[12];
  const float* sa_pb    = (const float*)d_in[13];
  const float* ca_qw    = (const float*)d_in[14];
  const float* ca_kvw   = (const float*)d_in[15];
  const float* ca_qb    = (const float*)d_in[16];
  const float* ca_vb    = (const float*)d_in[17];
  const float* ca_rpb   = (const float*)d_in[18];
  const float* ca_pw    = (const float*)d_in[19];
  const float* ca_pb    = (const float*)d_in[20];
  const float* fc1_w    = (const float*)d_in[21];
  const float* fc1_b    = (const float*)d_in[22];
  const float* fc2_w    = (const float*)d_in[23];
  const float* fc2_b    = (const float*)d_in[24];
  const float* g1       = (const float*)d_in[25];
  const float* g2       = (const float*)d_in[26];
  const float* g3       = (const float*)d_in[27];
  float* outf = (float*)d_out;     // f32 output; also cross-attn Q scratch
  float* qtf  = (float*)d_out;

  // Workspace: xf(16.9M) | hln(8.7M) | h1-union(34.6M) | bf16 pool(41.9M)
  char* w = (char*)d_ws;
  float* xf = (float*)w;  w += (size_t)MP * EDIM * 4;
  bf16* hln = (bf16*)w;   w += (size_t)MP * EDIM * 2;
  char* big = w;          w += (size_t)MP * FDIM * 2;
  const size_t qkv_sz = (size_t)4 * NHEAD * NQTOK * HD * 2;
  bf16* qt = (bf16*)big;
  bf16* kt = (bf16*)(big + qkv_sz);
  bf16* vt = (bf16*)(big + 2 * qkv_sz);
  bf16* h1 = (bf16*)big;
  bf16* wpool = (bf16*)w; w += 20971520UL * 2;
  const bool asy = ((size_t)(w - (char*)d_ws) <= ws_size);

  bf16* qkvw_b = wpool;
  bf16* pw_b   = qkvw_b + 3145728UL;
  bf16* cqw_b  = pw_b   + 1048576UL;
  bf16* ckvw_b = cqw_b  + 1048576UL;
  bf16* cpw_b  = ckvw_b + 2097152UL;
  bf16* fc1w_b = cpw_b  + 1048576UL;
  bf16* fc2w_b = fc1w_b + 4194304UL;
  bf16* y_b    = fc2w_b + 4194304UL;

  if (asy) {
    WPtrs wp = {{sa_qkv_w, sa_pw, ca_qw, ca_kvw, ca_pw, fc1_w, fc2_w, y}};
    conv_kernel<<<10240, 256, 0, stream>>>(wp, wpool);
  }
  zero_pads_kernel<<<dim3(((MP - MACT) * EDIM + 255) / 256), 256, 0, stream>>>(hln);
  hipMemsetAsync(qtf, 0, (size_t)MACT * EDIM * 4, stream);   // Q scratch

  // --- self-attention block ---
  ln_kernel<true><<<MACT, 256, 0, stream>>>(x, xf, hln, n1g, n1b);
  if (asy) gemm_bt<EPI_QKV, true><<<dim3(24, 33, 1), 256, 0, stream>>>(hln, qkvw_b, 1024, 1024,
      sa_qb, sa_vb, nullptr, nullptr, qt, kt, vt, nullptr);
  else     gemm_bt<EPI_QKV, false><<<dim3(24, 33, 1), 256, 0, stream>>>(hln, sa_qkv_w, 1024, 1024,
      sa_qb, sa_vb, nullptr, nullptr, qt, kt, vt, nullptr);
  attn_kernel<false><<<dim3(17, NHEAD, 4), 256, 0, stream>>>(qt, kt, vt, sa_rpb, hln);
  if (asy) gemm_bt<EPI_RES, true><<<dim3(8, 33, 2), 256, 0, stream>>>(hln, pw_b, 1024, 512,
      sa_pb, nullptr, g1, xf, nullptr, nullptr, nullptr, nullptr);
  else     gemm_bt<EPI_RES, false><<<dim3(8, 33, 2), 256, 0, stream>>>(hln, sa_pw, 1024, 512,
      sa_pb, nullptr, g1, xf, nullptr, nullptr, nullptr, nullptr);

  // --- cross-attention block ---
  ln_kernel<false><<<MACT, 256, 0, stream>>>(xf, nullptr, hln, n2g, n2b);
  if (asy) gemm_bt<EPI_Q, true><<<dim3(8, 33, 2), 256, 0, stream>>>(hln, cqw_b, 1024, 512,
      ca_qb, nullptr, nullptr, nullptr, nullptr, nullptr, nullptr, qtf);
  else     gemm_bt<EPI_Q, false><<<dim3(8, 33, 2), 256, 0, stream>>>(hln, ca_qw, 1024, 512,
      ca_qb, nullptr, nullptr, nullptr, nullptr, nullptr, nullptr, qtf);
  if (asy) gemm_bt<EPI_KV, true><<<dim3(16, 32, 1), 256, 0, stream>>>(y_b, ckvw_b, 1024, 1024,
      nullptr, ca_vb, nullptr, nullptr, kt, vt, nullptr, nullptr);
  else     gemm_bt<EPI_KV, false><<<dim3(16, 32, 1), 256, 0, stream>>>(y, ca_kvw, 1024, 1024,
      nullptr, ca_vb, nullptr, nullptr, kt, vt, nullptr, nullptr);
  attn_kernel<true><<<dim3(17, NHEAD, 4), 256, 0, stream>>>(qtf, kt, vt, ca_rpb, hln);
  if (asy) gemm_bt<EPI_RES, true><<<dim3(8, 33, 2), 256, 0, stream>>>(hln, cpw_b, 1024, 512,
      ca_pb, nullptr, g2, xf, nullptr, nullptr, nullptr, nullptr);
  else     gemm_bt<EPI_RES, false><<<dim3(8, 33, 2), 256, 0, stream>>>(hln, ca_pw, 1024, 512,
      ca_pb, nullptr, g2, xf, nullptr, nullptr, nullptr, nullptr);

  // --- FFN ---
  ln_kernel<false><<<MACT, 256, 0, stream>>>(xf, nullptr, hln, n3g, n3b);
  if (asy) gemm_bt<EPI_GELU, true><<<dim3(32, 33, 1), 256, 0, stream>>>(hln, fc1w_b, 1024, 1024,
      fc1_b, nullptr, nullptr, nullptr, h1, nullptr, nullptr, nullptr);
  else     gemm_bt<EPI_GELU, false><<<dim3(32, 33, 1), 256, 0, stream>>>(hln, fc1_w, 1024, 1024,
      fc1_b, nullptr, nullptr, nullptr, h1, nullptr, nullptr, nullptr);
  hipMemsetAsync(outf, 0, (size_t)MACT * EDIM * 4, stream);  // reset for final
  if (asy) gemm_bt<EPI_FINAL, true><<<dim3(8, 33, 4), 256, 0, stream>>>(h1, fc2w_b, 4096, 1024,
      fc2_b, nullptr, g3, xf, nullptr, nullptr, nullptr, outf);
  else     gemm_bt<EPI_FINAL, false><<<dim3(8, 33, 4), 256, 0, stream>>>(h1, fc2_w, 4096, 1024,
      fc2_b, nullptr, g3, xf, nullptr, nullptr, nullptr, outf);
}

// Round 9
// 826.830 us; speedup vs baseline: 1.6883x; 1.1362x over previous
//
#include <hip/hip_runtime.h>
#include <hip/hip_bf16.h>
#include <math.h>

typedef __bf16 bf16;
typedef __bf16 bf16x8 __attribute__((ext_vector_type(8)));
typedef float f32x4 __attribute__((ext_vector_type(4)));

#define MP    4224      // padded token rows (33*128)
#define MACT  4100      // B*N = 4*1025
#define NQTOK 1025
#define NKTOK 1024
#define EDIM  1024
#define FDIM  4096
#define NHEAD 16
#define HD    64
#define QSCALE 0.125f
#define VTS   1056      // self V^T row stride (16B-aligned, > 1025)

// ---- async global->LDS, 16B per lane; LDS base must be wave-uniform ----
__device__ __forceinline__ void glds16(const bf16* g, bf16* l) {
  __builtin_amdgcn_global_load_lds(
      (const __attribute__((address_space(1))) void*)g,
      (__attribute__((address_space(3))) void*)l, 16, 0, 0);
}

// scalar / 8-wide fp32->bf16 loads (fallback + conversion paths)
__device__ __forceinline__ bf16x8 ld8(const void* p, size_t i, bool f32) {
  if (f32) {
    const float* q = (const float*)p + i;
    bf16x8 r;
#pragma unroll
    for (int j = 0; j < 8; ++j) r[j] = (bf16)q[j];
    return r;
  }
  return *(const bf16x8*)((const bf16*)p + i);
}

// ---- weight/y fp32 -> bf16 pool conversion (one pass per launch) ----
struct WPtrs { const float* s[8]; };
__global__ __launch_bounds__(256) void conv_kernel(WPtrs wp, bf16* dst) {
  const size_t sz[8] = {3145728UL, 1048576UL, 1048576UL, 2097152UL,
                        1048576UL, 4194304UL, 4194304UL, 4194304UL};
  size_t id = ((size_t)blockIdx.x * 256 + threadIdx.x) * 8;
  size_t off = 0;
#pragma unroll
  for (int i = 0; i < 8; ++i) {
    if (id < off + sz[i]) {
      const float* s = wp.s[i] + (id - off);
      bf16x8 r;
#pragma unroll
      for (int j = 0; j < 8; ++j) r[j] = (bf16)s[j];
      *(bf16x8*)(dst + id) = r;
      return;
    }
    off += sz[i];
  }
}

// ---------------- zero the pad rows of hln ----------------
__global__ void zero_pads_kernel(bf16* hln) {
  int i = blockIdx.x * 256 + threadIdx.x;
  const int n = (MP - MACT) * EDIM;
  if (i < n) hln[(size_t)MACT * EDIM + i] = (bf16)0.0f;
}

// ---------------- LayerNorm (one block per token) ----------------
template<bool FIRST>
__global__ __launch_bounds__(256) void ln_kernel(const float* __restrict__ src,
    float* __restrict__ xf, bf16* __restrict__ out,
    const float* __restrict__ g, const float* __restrict__ bta) {
  const int row = blockIdx.x;
  const int tid = threadIdx.x;
  float v[4];
#pragma unroll
  for (int i = 0; i < 4; ++i) {
    v[i] = src[(size_t)row * EDIM + tid + i * 256];
    if (FIRST) xf[(size_t)row * EDIM + tid + i * 256] = v[i];
  }
  float s = 0.f, sq = 0.f;
#pragma unroll
  for (int i = 0; i < 4; ++i) { s += v[i]; sq += v[i] * v[i]; }
#pragma unroll
  for (int m = 32; m >= 1; m >>= 1) {
    s += __shfl_xor(s, m);
    sq += __shfl_xor(sq, m);
  }
  __shared__ float ss[4], ssq[4];
  const int wave = tid >> 6;
  if ((tid & 63) == 0) { ss[wave] = s; ssq[wave] = sq; }
  __syncthreads();
  s = ss[0] + ss[1] + ss[2] + ss[3];
  sq = ssq[0] + ssq[1] + ssq[2] + ssq[3];
  const float mean = s * (1.f / EDIM);
  const float var = sq * (1.f / EDIM) - mean * mean;
  const float rstd = rsqrtf(var + 1e-5f);
#pragma unroll
  for (int i = 0; i < 4; ++i) {
    int e = tid + i * 256;
    out[(size_t)row * EDIM + e] = (bf16)((v[i] - mean) * rstd * g[e] + bta[e]);
  }
}

// ---------------- GEMM: C[m,n] = sum_k A[m,k]*B[n,k], fused epilogues ----
// V outputs are written TRANSPOSED in global: V^T[(b,h,d), key].
enum { EPI_QKV = 0, EPI_KV = 1, EPI_Q = 2, EPI_RES = 3, EPI_GELU = 4, EPI_FINAL = 5 };

template<int EPI, bool ASY>
__global__ __launch_bounds__(256) void gemm_bt(
    const void* __restrict__ A, const void* __restrict__ Bw,
    int K, int Kc,
    const float* __restrict__ bias0, const float* __restrict__ bias1,
    const float* __restrict__ gamma, float* __restrict__ xf,
    bf16* __restrict__ out0, bf16* __restrict__ out1, bf16* __restrict__ out2,
    float* __restrict__ outf)
{
  constexpr int LDP = ASY ? 32 : 40;   // async needs contiguous rows (no pad)
  __shared__ bf16 As[128][LDP];
  __shared__ bf16 Bs[128][LDP];
  const int tid = threadIdx.x;
  const int lane = tid & 63, wave = tid >> 6;
  const int quad = lane >> 4, l16 = lane & 15;
  const int wr = wave >> 1, wc = wave & 1;
  const int m0 = blockIdx.y * 128, n0 = blockIdx.x * 128;
  const int kbase = blockIdx.z * Kc;
  const bool first = (blockIdx.z == 0);
  const int r0 = tid >> 2, c0 = (tid & 3) * 8;

  const bf16* gA = nullptr; const bf16* gB = nullptr;
  bf16* lA = nullptr; bf16* lB = nullptr;
  if (ASY) {
    gA = (const bf16*)A + (size_t)(m0 + wave * 16 + (lane >> 2)) * K + kbase + (lane & 3) * 8;
    gB = (const bf16*)Bw + (size_t)(n0 + wave * 16 + (lane >> 2)) * K + kbase + (lane & 3) * 8;
    lA = &As[wave * 16][0];
    lB = &Bs[wave * 16][0];
  }

  f32x4 acc[4][4];
#pragma unroll
  for (int i = 0; i < 4; ++i)
#pragma unroll
    for (int j = 0; j < 4; ++j)
#pragma unroll
      for (int r = 0; r < 4; ++r) acc[i][j][r] = 0.f;

  for (int k0 = 0; k0 < Kc; k0 += 32) {
    if (ASY) {
      glds16(gA, lA);
      glds16(gA + (size_t)64 * K, lA + 64 * 32);
      glds16(gB, lB);
      glds16(gB + (size_t)64 * K, lB + 64 * 32);
      gA += 32; gB += 32;
    } else {
      const bool f32a = (EPI == EPI_KV);   // fallback: y fp32, weights fp32
      const size_t kk = (size_t)(kbase + k0);
      *(bf16x8*)(&As[r0][c0])      = ld8(A,  (size_t)(m0 + r0) * K + kk + c0, f32a);
      *(bf16x8*)(&As[r0 + 64][c0]) = ld8(A,  (size_t)(m0 + r0 + 64) * K + kk + c0, f32a);
      *(bf16x8*)(&Bs[r0][c0])      = ld8(Bw, (size_t)(n0 + r0) * K + kk + c0, true);
      *(bf16x8*)(&Bs[r0 + 64][c0]) = ld8(Bw, (size_t)(n0 + r0 + 64) * K + kk + c0, true);
    }
    __syncthreads();
    bf16x8 af[4], bfv[4];
#pragma unroll
    for (int i = 0; i < 4; ++i) {
      af[i]  = *(const bf16x8*)(&As[wr * 64 + i * 16 + l16][quad * 8]);
      bfv[i] = *(const bf16x8*)(&Bs[wc * 64 + i * 16 + l16][quad * 8]);
    }
#pragma unroll
    for (int mb = 0; mb < 4; ++mb)
#pragma unroll
      for (int nb = 0; nb < 4; ++nb)
        acc[mb][nb] = __builtin_amdgcn_mfma_f32_16x16x32_bf16(af[mb], bfv[nb], acc[mb][nb], 0, 0, 0);
    __syncthreads();
  }

  // epilogue
#pragma unroll
  for (int mb = 0; mb < 4; ++mb) {
#pragma unroll
    for (int r = 0; r < 4; ++r) {
      const int gm = m0 + wr * 64 + mb * 16 + quad * 4 + r;
#pragma unroll
      for (int nb = 0; nb < 4; ++nb) {
        const int gn = n0 + wc * 64 + nb * 16 + l16;
        float v = acc[mb][nb][r];
        if (EPI == EPI_QKV) {
          if (gm < MACT) {
            unsigned b = (unsigned)gm / 1025u;
            unsigned t = (unsigned)gm - b * 1025u;
            int sec = gn >> 10, e = gn & 1023;
            int h = e >> 6, d = e & 63;
            if (sec == 0)
              out0[((size_t)(b * NHEAD + h) * NQTOK + t) * HD + d] =
                  (bf16)((v + bias0[e]) * QSCALE);
            else if (sec == 1)
              out1[((size_t)(b * NHEAD + h) * NQTOK + t) * HD + d] = (bf16)v;
            else   // V transposed: row = d, col = token
              out2[((size_t)(b * NHEAD + h) * HD + d) * VTS + t] =
                  (bf16)(v + bias1[e]);
          }
        } else if (EPI == EPI_KV) {
          unsigned b = (unsigned)gm >> 10;
          unsigned t = (unsigned)gm & 1023u;
          int sec = gn >> 10, e = gn & 1023;
          int h = e >> 6, d = e & 63;
          if (sec == 0)
            out0[((size_t)(b * NHEAD + h) * NKTOK + t) * HD + d] = (bf16)v;
          else   // V transposed, stride NKTOK (1024, aligned)
            out1[((size_t)(b * NHEAD + h) * HD + d) * NKTOK + t] =
                (bf16)(v + bias1[e]);
        } else if (EPI == EPI_Q) {
          if (gm < MACT) {
            unsigned b = (unsigned)gm / 1025u;
            unsigned t = (unsigned)gm - b * 1025u;
            int h = gn >> 6, d = gn & 63;
            float add = (v + (first ? bias0[gn] : 0.f)) * QSCALE;
            atomicAdd(&outf[((size_t)(b * NHEAD + h) * NQTOK + t) * HD + d], add);
          }
        } else if (EPI == EPI_RES) {
          if (gm < MACT) {
            float add = gamma[gn] * (v + (first ? bias0[gn] : 0.f));
            atomicAdd(&xf[(size_t)gm * EDIM + gn], add);
          }
        } else if (EPI == EPI_GELU) {
          float z = v + bias0[gn];
          float ge = 0.5f * z * (1.0f + erff(z * 0.70710678118f));
          out0[(size_t)gm * FDIM + gn] = (bf16)ge;
        } else { // EPI_FINAL: d_out f32, zeroed before launch
          if (gm < MACT) {
            size_t o = (size_t)gm * EDIM + gn;
            float add = gamma[gn] * (v + (first ? bias0[gn] : 0.f));
            if (first) add += xf[o];
            atomicAdd(&outf[o], add);
          }
        }
      }
    }
  }
}

// ---------------- Flash attention (self: causal+rpb, cross: rpb) --------
// grid (17, H, B), block 256 = 4 waves; 64-query tile, 64-key chunks.
// V arrives TRANSPOSED from the producer GEMM -> conflict-free b128 staging.
// K/V global loads software-pipelined one chunk ahead (regs), 2 barriers/chunk.
template<bool CROSS>
__global__ __launch_bounds__(256) void attn_kernel(
    const void* __restrict__ Q, const bf16* __restrict__ Kg,
    const bf16* __restrict__ Vg, const float* __restrict__ rpb,
    bf16* __restrict__ out)
{
  const int NK  = CROSS ? NKTOK : NQTOK;
  const int NRD = CROSS ? 3970 : 3972;
  const int VS  = CROSS ? NKTOK : VTS;     // V^T row stride
  const int qt  = CROSS ? blockIdx.x : (16 - blockIdx.x);  // heavy blocks first
  const int h = blockIdx.y, b = blockIdx.z;
  const int tid = threadIdx.x;
  const int lane = tid & 63, wave = tid >> 6;
  const int quad = lane >> 4, l16 = lane & 15;

  __shared__ bf16 rpb_s[4096];
  __shared__ bf16 Ks[64][72];
  __shared__ bf16 Vt[64][72];        // V^T tile: [d][key]
  __shared__ bf16 Ps[4][16][72];     // per-wave P round-trip

  for (int i = tid; i < 4096; i += 256)
    rpb_s[i] = (bf16)((i < NRD) ? rpb[(size_t)i * NHEAD + h] : 0.f);

  const int q0 = qt * 64;
  const int qrow = q0 + wave * 16 + l16;
  const size_t qhb = (size_t)(b * NHEAD + h) * NQTOK;
  bf16x8 qf0, qf1;
  if (qrow < NQTOK) {
    if (CROSS) {
      const float* Qf = (const float*)Q + (qhb + qrow) * HD;
#pragma unroll
      for (int j = 0; j < 8; ++j) {
        qf0[j] = (bf16)Qf[quad * 8 + j];
        qf1[j] = (bf16)Qf[32 + quad * 8 + j];
      }
    } else {
      const bf16* Qb = (const bf16*)Q;
      qf0 = *(const bf16x8*)(Qb + (qhb + qrow) * HD + quad * 8);
      qf1 = *(const bf16x8*)(Qb + (qhb + qrow) * HD + 32 + quad * 8);
    }
  } else {
#pragma unroll
    for (int j = 0; j < 8; ++j) { qf0[j] = (bf16)0.f; qf1[j] = (bf16)0.f; }
  }

  // hoisted rpb row codes: idx = qcode[r] - kcode for interior pixels
  int qgv[4], qcode[4];
#pragma unroll
  for (int r = 0; r < 4; ++r) {
    int qg = q0 + wave * 16 + quad * 4 + r;
    qgv[r] = qg;
    int p = qg - 1;
    qcode[r] = (qg > 0) ? ((p >> 5) * 63 + (p & 31) + 1984) : 0;
  }

  float m_run[4], l_run[4];
  f32x4 oacc[4];
#pragma unroll
  for (int r = 0; r < 4; ++r) { m_run[r] = -1e30f; l_run[r] = 0.f; }
#pragma unroll
  for (int d = 0; d < 4; ++d)
#pragma unroll
    for (int r = 0; r < 4; ++r) oacc[d][r] = 0.f;

  const size_t kvbK = (size_t)(b * NHEAD + h) * NK;
  const size_t vbase = (size_t)(b * NHEAD + h) * HD;
  const int nch = CROSS ? (NKTOK / 64) : (qt + 1);

  const int rr = tid >> 3;            // 0..31 (+32 with vv)
  const int co = (tid & 7) * 8;

  bf16x8 krg[2], vrg[2];
  auto stage_load = [&](int c) {
    const int kc = c * 64;
#pragma unroll
    for (int vv = 0; vv < 2; ++vv) {
      const int row = rr + vv * 32;
      // K: natural layout row=key
      if (!CROSS && kc + row >= NK) {
#pragma unroll
        for (int j = 0; j < 8; ++j) krg[vv][j] = (bf16)0.f;
      } else {
        krg[vv] = *(const bf16x8*)(Kg + (kvbK + kc + row) * HD + co);
      }
      // V^T: row=d, col=key
      if (!CROSS && kc + co >= NK) {
#pragma unroll
        for (int j = 0; j < 8; ++j) vrg[vv][j] = (bf16)0.f;
      } else {
        vrg[vv] = *(const bf16x8*)(Vg + (vbase + row) * VS + kc + co);
      }
    }
  };

  stage_load(0);
  for (int c = 0; c < nch; ++c) {
    const int kc = c * 64;
    if (c) __syncthreads();
#pragma unroll
    for (int vv = 0; vv < 2; ++vv) {
      const int row = rr + vv * 32;
      *(bf16x8*)(&Ks[row][co]) = krg[vv];
      *(bf16x8*)(&Vt[row][co]) = vrg[vv];
    }
    __syncthreads();
    if (c + 1 < nch) stage_load(c + 1);   // prefetch overlaps compute

    // ---- S = Q K^T + bias (+causal) ----
    float sv[4][4];
#pragma unroll
    for (int kb = 0; kb < 4; ++kb) {
      f32x4 a;
#pragma unroll
      for (int r = 0; r < 4; ++r) a[r] = 0.f;
      bf16x8 kf0 = *(const bf16x8*)(&Ks[kb * 16 + l16][quad * 8]);
      bf16x8 kf1 = *(const bf16x8*)(&Ks[kb * 16 + l16][32 + quad * 8]);
      a = __builtin_amdgcn_mfma_f32_16x16x32_bf16(qf0, kf0, a, 0, 0, 0);
      a = __builtin_amdgcn_mfma_f32_16x16x32_bf16(qf1, kf1, a, 0, 0, 0);
      const int kg = kc + kb * 16 + l16;
      int kcode;
      if (CROSS) kcode = (kg >> 5) * 63 + (kg & 31);
      else {
        int k1 = kg - 1;
        kcode = (kg > 0) ? ((k1 >> 5) * 63 + (k1 & 31)) : 0;
      }
#pragma unroll
      for (int r = 0; r < 4; ++r) {
        const int qg = qgv[r];
        bool valid = (kg < NK) && (CROSS || kg <= qg);
        int idx;
        if (CROSS) {
          idx = (qg == 0) ? 3969 : (qcode[r] - kcode);
        } else {
          idx = (qg == 0) ? ((kg == 0) ? 3971 : 3969)
                          : ((kg == 0) ? 3970 : (qcode[r] - kcode));
        }
        sv[kb][r] = valid ? (a[r] + (float)rpb_s[idx]) : -1e30f;
      }
    }

    // ---- online softmax ----
#pragma unroll
    for (int r = 0; r < 4; ++r) {
      float mx = fmaxf(fmaxf(sv[0][r], sv[1][r]), fmaxf(sv[2][r], sv[3][r]));
#pragma unroll
      for (int mk = 8; mk >= 1; mk >>= 1) mx = fmaxf(mx, __shfl_xor(mx, mk));
      const float mnew = fmaxf(m_run[r], mx);
      const float alpha = __expf(m_run[r] - mnew);
      m_run[r] = mnew;
      float rs = 0.f;
#pragma unroll
      for (int kb = 0; kb < 4; ++kb) {
        float p = __expf(sv[kb][r] - mnew);
        rs += p;
        Ps[wave][quad * 4 + r][kb * 16 + l16] = (bf16)p;
      }
#pragma unroll
      for (int mk = 8; mk >= 1; mk >>= 1) rs += __shfl_xor(rs, mk);
      l_run[r] = l_run[r] * alpha + rs;
#pragma unroll
      for (int d = 0; d < 4; ++d) oacc[d][r] *= alpha;
    }

    // ---- O += P V (Ps round-trip intra-wave; Vt fragments are b128) ----
    bf16x8 pf0 = *(const bf16x8*)(&Ps[wave][l16][quad * 8]);
    bf16x8 pf1 = *(const bf16x8*)(&Ps[wave][l16][32 + quad * 8]);
#pragma unroll
    for (int db = 0; db < 4; ++db) {
      bf16x8 vf0 = *(const bf16x8*)(&Vt[db * 16 + l16][quad * 8]);
      bf16x8 vf1 = *(const bf16x8*)(&Vt[db * 16 + l16][32 + quad * 8]);
      oacc[db] = __builtin_amdgcn_mfma_f32_16x16x32_bf16(pf0, vf0, oacc[db], 0, 0, 0);
      oacc[db] = __builtin_amdgcn_mfma_f32_16x16x32_bf16(pf1, vf1, oacc[db], 0, 0, 0);
    }
  }

  // ---- write O ----
#pragma unroll
  for (int r = 0; r < 4; ++r) {
    const int qg = qgv[r];
    if (qg < NQTOK) {
      const float inv = 1.f / l_run[r];
      const size_t row = (size_t)b * NQTOK + qg;
#pragma unroll
      for (int db = 0; db < 4; ++db)
        out[row * EDIM + h * HD + db * 16 + l16] = (bf16)(oacc[db][r] * inv);
    }
  }
}

// ---------------- launch ----------------
extern "C" void kernel_launch(void* const* d_in, const int* in_sizes, int n_in,
                              void* d_out, int out_size, void* d_ws, size_t ws_size,
                              hipStream_t stream) {
  (void)in_sizes; (void)n_in; (void)out_size;
  const float* x        = (const float*)d_in[0];
  const float* y        = (const float*)d_in[1];
  const float* n1g      = (const float*)d_in[2];
  const float* n1b      = (const float*)d_in[3];
  const float* n2g      = (const float*)d_in[4];
  const float* n2b      = (const float*)d_in[5];
  const float* n3g      = (const float*)d_in[6];
  const float* n3b      = (const float*)d_in[7];
  const float* sa_qkv_w = (const float*)d_in[8];
  const float* sa_qb    = (const float*)d_in[9];
  const float* sa_vb    = (const float*)d_in[10];
  const float* sa_rpb   = (const float*)d_in[11];
  const float* sa_pw    = (const float*)d_in[12];
  const float* sa_pb    = (const float*)d_in[13];
  const float* ca_qw    = (const float*)d_in[14];
  const float* ca_kvw   = (const float*)d_in[15];
  const float* ca_qb    = (const float*)d_in[16];
  const float* ca_vb    = (const float*)d_in[17];
  const float* ca_rpb   = (const float*)d_in[18];
  const float* ca_pw    = (const float*)d_in[19];
  const float* ca_pb    = (const float*)d_in[20];
  const float* fc1_w    = (const float*)d_in[21];
  const float* fc1_b    = (const float*)d_in[22];
  const float* fc2_w    = (const float*)d_in[23];
  const float* fc2_b    = (const float*)d_in[24];
  const float* g1       = (const float*)d_in[25];
  const float* g2       = (const float*)d_in[26];
  const float* g3       = (const float*)d_in[27];
  float* outf = (float*)d_out;     // f32 output; also cross-attn Q scratch
  float* qtf  = (float*)d_out;

  // Workspace: xf(16.9M) | hln(8.7M) | h1-union(34.6M) | bf16 pool(41.9M)
  char* w = (char*)d_ws;
  float* xf = (float*)w;  w += (size_t)MP * EDIM * 4;
  bf16* hln = (bf16*)w;   w += (size_t)MP * EDIM * 2;
  char* big = w;          w += (size_t)MP * FDIM * 2;
  const size_t qkv_sz = (size_t)4 * NHEAD * NQTOK * HD * 2;       // 8.40 MB
  bf16* qt = (bf16*)big;
  bf16* kt = (bf16*)(big + qkv_sz);
  bf16* vt = (bf16*)(big + 2 * qkv_sz);   // V^T (8.65M self; union has room)
  bf16* h1 = (bf16*)big;
  bf16* wpool = (bf16*)w; w += 20971520UL * 2;
  const bool asy = ((size_t)(w - (char*)d_ws) <= ws_size);

  bf16* qkvw_b = wpool;
  bf16* pw_b   = qkvw_b + 3145728UL;
  bf16* cqw_b  = pw_b   + 1048576UL;
  bf16* ckvw_b = cqw_b  + 1048576UL;
  bf16* cpw_b  = ckvw_b + 2097152UL;
  bf16* fc1w_b = cpw_b  + 1048576UL;
  bf16* fc2w_b = fc1w_b + 4194304UL;
  bf16* y_b    = fc2w_b + 4194304UL;

  if (asy) {
    WPtrs wp = {{sa_qkv_w, sa_pw, ca_qw, ca_kvw, ca_pw, fc1_w, fc2_w, y}};
    conv_kernel<<<10240, 256, 0, stream>>>(wp, wpool);
  }
  zero_pads_kernel<<<dim3(((MP - MACT) * EDIM + 255) / 256), 256, 0, stream>>>(hln);
  hipMemsetAsync(qtf, 0, (size_t)MACT * EDIM * 4, stream);   // Q scratch

  // --- self-attention block ---
  ln_kernel<true><<<MACT, 256, 0, stream>>>(x, xf, hln, n1g, n1b);
  if (asy) gemm_bt<EPI_QKV, true><<<dim3(24, 33, 1), 256, 0, stream>>>(hln, qkvw_b, 1024, 1024,
      sa_qb, sa_vb, nullptr, nullptr, qt, kt, vt, nullptr);
  else     gemm_bt<EPI_QKV, false><<<dim3(24, 33, 1), 256, 0, stream>>>(hln, sa_qkv_w, 1024, 1024,
      sa_qb, sa_vb, nullptr, nullptr, qt, kt, vt, nullptr);
  attn_kernel<false><<<dim3(17, NHEAD, 4), 256, 0, stream>>>(qt, kt, vt, sa_rpb, hln);
  if (asy) gemm_bt<EPI_RES, true><<<dim3(8, 33, 2), 256, 0, stream>>>(hln, pw_b, 1024, 512,
      sa_pb, nullptr, g1, xf, nullptr, nullptr, nullptr, nullptr);
  else     gemm_bt<EPI_RES, false><<<dim3(8, 33, 2), 256, 0, stream>>>(hln, sa_pw, 1024, 512,
      sa_pb, nullptr, g1, xf, nullptr, nullptr, nullptr, nullptr);

  // --- cross-attention block ---
  ln_kernel<false><<<MACT, 256, 0, stream>>>(xf, nullptr, hln, n2g, n2b);
  if (asy) gemm_bt<EPI_Q, true><<<dim3(8, 33, 2), 256, 0, stream>>>(hln, cqw_b, 1024, 512,
      ca_qb, nullptr, nullptr, nullptr, nullptr, nullptr, nullptr, qtf);
  else     gemm_bt<EPI_Q, false><<<dim3(8, 33, 2), 256, 0, stream>>>(hln, ca_qw, 1024, 512,
      ca_qb, nullptr, nullptr, nullptr, nullptr, nullptr, nullptr, qtf);
  if (asy) gemm_bt<EPI_KV, true><<<dim3(16, 32, 1), 256, 0, stream>>>(y_b, ckvw_b, 1024, 1024,
      nullptr, ca_vb, nullptr, nullptr, kt, vt, nullptr, nullptr);
  else     gemm_bt<EPI_KV, false><<<dim3(16, 32, 1), 256, 0, stream>>>(y, ca_kvw, 1024, 1024,
      nullptr, ca_vb, nullptr, nullptr, kt, vt, nullptr, nullptr);
  attn_kernel<true><<<dim3(17, NHEAD, 4), 256, 0, stream>>>(qtf, kt, vt, ca_rpb, hln);  // 17 tiles!
  if (asy) gemm_bt<EPI_RES, true><<<dim3(8, 33, 2), 256, 0, stream>>>(hln, cpw_b, 1024, 512,
      ca_pb, nullptr, g2, xf, nullptr, nullptr, nullptr, nullptr);
  else     gemm_bt<EPI_RES, false><<<dim3(8, 33, 2), 256, 0, stream>>>(hln, ca_pw, 1024, 512,
      ca_pb, nullptr, g2, xf, nullptr, nullptr, nullptr, nullptr);

  // --- FFN ---
  ln_kernel<false><<<MACT, 256, 0, stream>>>(xf, nullptr, hln, n3g, n3b);
  if (asy) gemm_bt<EPI_GELU, true><<<dim3(32, 33, 1), 256, 0, stream>>>(hln, fc1w_b, 1024, 1024,
      fc1_b, nullptr, nullptr, nullptr, h1, nullptr, nullptr, nullptr);
  else     gemm_bt<EPI_GELU, false><<<dim3(32, 33, 1), 256, 0, stream>>>(hln, fc1_w, 1024, 1024,
      fc1_b, nullptr, nullptr, nullptr, h1, nullptr, nullptr, nullptr);
  hipMemsetAsync(outf, 0, (size_t)MACT * EDIM * 4, stream);  // reset for final
  if (asy) gemm_bt<EPI_FINAL, true><<<dim3(8, 33, 4), 256, 0, stream>>>(h1, fc2w_b, 4096, 1024,
      fc2_b, nullptr, g3, xf, nullptr, nullptr, nullptr, outf);
  else     gemm_bt<EPI_FINAL, false><<<dim3(8, 33, 4), 256, 0, stream>>>(h1, fc2_w, 4096, 1024,
      fc2_b, nullptr, g3, xf, nullptr, nullptr, nullptr, outf);
}